// Round 9
// baseline (3510.418 us; speedup 1.0000x reference)
//
#include <hip/hip_runtime.h>

// ---------------------------------------------------------------------------
// MiniMax-M1 Lightning Attention forward, MI355X / gfx950.
//   0. cast fp32->bf16: hidden, w_qkv(+w_gate contiguous)
//   1. fused qkv+gate via 256x256 BK=32 lockstep GEMM (64KB LDS -> 2 blk/CU)
//      epilogue: q,k,gate row-major; v stored DIRECTLY transposed (vT)
//   2. transpose_k: kTs[d][m] = silu_k[m][d] * exp(-s*(255-m))
//   3. KVT_j = vT @ kTs^T  (= KV_j^T, fp32)
//   4. scan: S_{j+1} = e^{-256 s} S_j + KV_j ; store S_j^T bf16  [512 WGs]
//   5. P = (q k^T) * diag_decay  per block   [2 half-launches, 1-slot P buffer]
//   6. intra+inter fused: acc = q @ S^T; acc *= q_decay(row); acc += P @ v
//   7. y = gate * rmsnorm(attn) * norm_w
//   8. out = y @ w_out^T via same 256 GEMM [fp32 -> d_out]
// Workspace: 7 slots x 33,554,432 B = 234,881,024 B peak (proven to fit).
// ---------------------------------------------------------------------------

typedef unsigned short u16;
typedef __bf16 bf16x8 __attribute__((ext_vector_type(8)));
typedef float f32x4 __attribute__((ext_vector_type(4)));

#define SEQ 4096
#define HID 2048

__device__ __forceinline__ u16 f2bf(float f) {
    union { float f; unsigned u; } v; v.f = f;
    unsigned r = v.u + 0x7fffu + ((v.u >> 16) & 1u);   // round-to-nearest-even
    return (u16)(r >> 16);
}
__device__ __forceinline__ float bf2f(u16 u) {
    union { unsigned u; float f; } v; v.u = ((unsigned)u) << 16; return v.f;
}

// async global->LDS, 16B per lane; lds dest must be wave-uniform base (+lane*16)
typedef __attribute__((address_space(1))) unsigned char gas_u8;
typedef __attribute__((address_space(3))) unsigned char las_u8;
__device__ __forceinline__ void gld16(const void* g, void* l) {
    __builtin_amdgcn_global_load_lds((gas_u8*)g, (las_u8*)l, 16, 0, 0);
}

// ---------------------------------------------------------------------------
// fp32 -> bf16 cast, 4 elems/thread, exact grids (n % 1024 == 0)
// ---------------------------------------------------------------------------
__global__ __launch_bounds__(256) void castk(const float* __restrict__ in,
                                             u16* __restrict__ out) {
    const size_t i = (size_t)blockIdx.x * 256 + threadIdx.x;
    const float4 f = *(const float4*)&in[i * 4];
    uint2 o;
    o.x = (unsigned)f2bf(f.x) | ((unsigned)f2bf(f.y) << 16);
    o.y = (unsigned)f2bf(f.z) | ((unsigned)f2bf(f.w) << 16);
    *(uint2*)&out[i * 4] = o;
}

// ---------------------------------------------------------------------------
// 256x256-tile BK=32 lockstep pipelined NT GEMM (C = A[Mx2048] * B[Nx2048]^T).
// 512 threads = 8 waves (2M x 4N), each wave 128x64 out (8x4 16x16 frags).
// LDS 64 KiB: 2 K-tile buffers x (A 256x32 + B 256x32) bf16 -> 2 blocks/CU,
// so one block's MFMA phases fill the other's barrier/drain stalls.
// Swizzle (64B rows): physical chunk = logical ^ ((row>>2)&3), applied as
// inverse-swizzled GLOBAL source (linear global_load_lds dest) + swizzled
// ds_read; max 2-way bank alias (free).  Counted vmcnt(3) once per K-tile;
// lgkm(4) stagger on the 6-read phase; setprio(1) around each 8-MFMA burst.
// MODE 0: fused QKV+gate epilogue; MODE 1: f32 out.
// ---------------------------------------------------------------------------
template <int MODE>
__global__ __launch_bounds__(512, 4) void gemm256(const u16* __restrict__ A,
                                                  const u16* __restrict__ Bm,
                                                  void* __restrict__ Cv,
                                                  void* __restrict__ aux,
                                                  void* __restrict__ aux2) {
    constexpr int NTN = (MODE == 0) ? 32 : 8;     // tiles along N
    constexpr int NT  = 64;                       // K tiles (2048 / 32)
    extern __shared__ u16 smem[];                 // [2][A 8192 | B 8192] elems

    // XCD swizzle: 8 XCDs; per-XCD 4-row x 8-col rectangular supertiles
    const int bid = blockIdx.x;
    const int xcd = bid & 7, l = bid >> 3;
    int tm, tn;
    if constexpr (MODE == 0) {       // 32x32 tile grid, 128 WGs per XCD
        tm = xcd * 4 + (l & 3);
        tn = ((l >> 2) & 7) | ((l >> 5) << 3);
    } else {                         // 32x8 grid, 32 WGs per XCD (4x8 rect)
        const int wgid = xcd * 32 + l;
        tm = wgid / NTN; tn = wgid % NTN;
    }

    const int tid  = threadIdx.x;
    const int lane = tid & 63, wv = tid >> 6;
    const int quad = lane >> 4, cl = lane & 15;
    const int wm = (wv & 1) * 128, wn = (wv >> 1) * 64;

    // staging: thread t covers row tid>>2 (0..127 per half-tile issue),
    // 16B chunk tid&3; global chunk pre-XORed with (row>>2)&3 so the linear
    // LDS dest holds the swizzled layout
    const int srw  = tid >> 2;
    const int colo = ((tid & 3) ^ ((srw >> 2) & 3)) * 8;
    const u16* gA0 = A  + (size_t)(tm * 256 + srw) * HID + colo;
    const u16* gB0 = Bm + (size_t)(tn * 256 + srw) * HID + colo;

    // ds_read swizzle: physical chunk = quad ^ ((cl>>2)&3)  (frag row base is
    // 16-aligned so (row>>2)&3 == (cl>>2)&3)
    const int x0 = (quad ^ ((cl >> 2) & 3)) * 8;

    f32x4 acc[8][4];
    const f32x4 zero = {0.f, 0.f, 0.f, 0.f};
    #pragma unroll
    for (int a = 0; a < 8; a++)
        #pragma unroll
        for (int b = 0; b < 4; b++) acc[a][b] = zero;

    bf16x8 af[4], b0[2], b1[2];

    auto STG = [&](int kt, int mat, int hh) {   // stage one 128x32 half-tile
        const u16* g = (mat ? gB0 : gA0) + (size_t)(hh * 128) * HID + kt * 32;
        u16* lp = smem + (kt & 1) * 16384 + mat * 8192 + hh * 4096 + wv * 512;
        gld16(g, lp);
    };
    auto LDA = [&](int qm, int ab) {
        #pragma unroll
        for (int mi = 0; mi < 4; mi++)
            af[mi] = *(const bf16x8*)&smem[(wm + qm * 64 + mi * 16 + cl) * 32 + ab + x0];
    };
    auto LDB = [&](bf16x8* d, int qn, int bb2) {
        #pragma unroll
        for (int ni = 0; ni < 2; ni++)
            d[ni] = *(const bf16x8*)&smem[(wn + qn * 32 + ni * 16 + cl) * 32 + bb2 + x0];
    };
    auto MM = [&](int qm, int qn, const bf16x8* bv) {
        #pragma unroll
        for (int mi = 0; mi < 4; mi++)
            #pragma unroll
            for (int ni = 0; ni < 2; ni++)
                acc[qm * 4 + mi][qn * 2 + ni] =
                    __builtin_amdgcn_mfma_f32_16x16x32_bf16(af[mi], bv[ni],
                        acc[qm * 4 + mi][qn * 2 + ni], 0, 0, 0);
    };

    // prologue: issue stream per tile = B.lo, B.hi, A.lo, A.hi (1 load each)
    STG(0, 1, 0); STG(0, 1, 1); STG(0, 0, 0); STG(0, 0, 1);
    STG(1, 1, 0); STG(1, 1, 1); STG(1, 0, 0);
    asm volatile("s_waitcnt vmcnt(3)" ::: "memory");   // tile 0 resident
    __builtin_amdgcn_s_barrier();

    #pragma unroll 2
    for (int t = 0; t < NT; ++t) {
        const int ab  = (t & 1) * 16384;
        const int bb2 = ab + 8192;
        // phase 0: C(0,0); issue (t+1).A.hi
        LDA(0, ab); LDB(b0, 0, bb2);
        if (t + 1 < NT) STG(t + 1, 0, 1);
        asm volatile("s_waitcnt lgkmcnt(4)" ::: "memory");  // stagger drain
        __builtin_amdgcn_s_barrier();
        asm volatile("s_waitcnt lgkmcnt(0)" ::: "memory");
        __builtin_amdgcn_s_setprio(1); MM(0, 0, b0); __builtin_amdgcn_s_setprio(0);
        __builtin_amdgcn_s_barrier();
        // phase 1: C(0,1); issue (t+2).B.lo  [B dead after this phase]
        LDB(b1, 1, bb2);
        if (t + 2 < NT) STG(t + 2, 1, 0);
        __builtin_amdgcn_s_barrier();
        asm volatile("s_waitcnt lgkmcnt(0)" ::: "memory");
        __builtin_amdgcn_s_setprio(1); MM(0, 1, b1); __builtin_amdgcn_s_setprio(0);
        __builtin_amdgcn_s_barrier();
        // phase 2: C(1,1); issue (t+2).B.hi
        LDA(1, ab);
        if (t + 2 < NT) STG(t + 2, 1, 1);
        __builtin_amdgcn_s_barrier();
        asm volatile("s_waitcnt lgkmcnt(0)" ::: "memory");
        __builtin_amdgcn_s_setprio(1); MM(1, 1, b1); __builtin_amdgcn_s_setprio(0);
        __builtin_amdgcn_s_barrier();
        // phase 3: C(1,0); issue (t+2).A.lo; boundary wait: keep newest 3
        // ((t+2).B.lo,B.hi,A.lo) -> everything through (t+1).A.hi landed
        if (t + 2 < NT) {
            STG(t + 2, 0, 0);
            asm volatile("s_waitcnt vmcnt(3)" ::: "memory");
        } else {
            asm volatile("s_waitcnt vmcnt(0)" ::: "memory");
        }
        __builtin_amdgcn_s_barrier();
        __builtin_amdgcn_s_setprio(1); MM(1, 0, b0); __builtin_amdgcn_s_setprio(0);
        __builtin_amdgcn_s_barrier();
    }

    // epilogue: m = tm*256 + wm + (a>>2)*64 + (a&3)*16 + quad*4 + r
    //           n = tn*256 + wn + (b>>1)*32 + (b&1)*16 + cl
    if constexpr (MODE == 0) {
        // 128-col group is wave-uniform: grp 0-15 q | 16-31 k | 32-47 v | 48-63 gate
        const int grp = tn * 2 + (wn >> 7);
        const int which = grp >> 4, hd = grp & 15;
        const int n64 = wn & 64;
        if (which == 2) {
            // vT[bz][d][m]: lane holds 4 consecutive m at fixed d -> uint2
            const size_t bz = (size_t)((tm >> 4) * 256 + hd * 16 + (tm & 15));
            u16* tdst = (u16*)aux + bz * 32768;
            #pragma unroll
            for (int a = 0; a < 8; a++) {
                const int mm = wm + (a >> 2) * 64 + (a & 3) * 16 + quad * 4;
                #pragma unroll
                for (int b = 0; b < 4; b++) {
                    const int d = n64 + (b >> 1) * 32 + (b & 1) * 16 + cl;
                    u16 p[4];
                    #pragma unroll
                    for (int r = 0; r < 4; r++) {
                        const float x = acc[a][b][r];
                        p[r] = f2bf(x / (1.f + __expf(-x)));
                    }
                    uint2 pk;
                    pk.x = (unsigned)p[0] | ((unsigned)p[1] << 16);
                    pk.y = (unsigned)p[2] | ((unsigned)p[3] << 16);
                    *(uint2*)&tdst[(size_t)d * 256 + mm] = pk;
                }
            }
            return;
        }
        u16* dst = (which == 0) ? (u16*)Cv
                 : (which == 1) ? (u16*)Cv + (size_t)16777216   // k slot (S1)
                                : (u16*)aux2;                   // gate slot
        #pragma unroll
        for (int a = 0; a < 8; a++)
            #pragma unroll
            for (int b = 0; b < 4; b++)
                #pragma unroll
                for (int r = 0; r < 4; r++) {
                    const int m = tm * 256 + wm + (a >> 2) * 64 + (a & 3) * 16 + quad * 4 + r;
                    const int col = hd * 128 + n64 + (b >> 1) * 32 + (b & 1) * 16 + cl;
                    const float x = acc[a][b][r];
                    const float v = (which == 3) ? 1.f / (1.f + __expf(-x))
                                                 : x / (1.f + __expf(-x));
                    dst[(size_t)m * HID + col] = f2bf(v);
                }
        return;
    } else {
        float* C = (float*)Cv;
        #pragma unroll
        for (int a = 0; a < 8; a++)
            #pragma unroll
            for (int b = 0; b < 4; b++)
                #pragma unroll
                for (int r = 0; r < 4; r++) {
                    const int m = tm * 256 + wm + (a >> 2) * 64 + (a & 3) * 16 + quad * 4 + r;
                    const int n = tn * 256 + wn + (b >> 1) * 32 + (b & 1) * 16 + cl;
                    C[(size_t)m * HID + n] = acc[a][b][r];
                }
    }
}

// ---------------------------------------------------------------------------
// Generic 128x128-tile NT GEMM for the small per-(b,h,block) ops.
// ---------------------------------------------------------------------------
#define M_QKV   0
#define M_P     2
#define M_INTRA 3
#define M_KVT   4
#define M_OUT   6

template <int MODE>
__global__ __launch_bounds__(256) void gemm_nt(const u16* __restrict__ A,
                                               const u16* __restrict__ Bm,
                                               void* __restrict__ Cv,
                                               const float* __restrict__ slope,
                                               int bz0,
                                               void* __restrict__ aux,
                                               void* __restrict__ aux2) {
    constexpr int NPH = (MODE == M_INTRA) ? 2 : 1;
    const int tid = threadIdx.x;
    const int tm = blockIdx.x, tn = blockIdx.y;
    const int bzl = blockIdx.z;           // local z (P buffer index)
    const int bz  = bzl + bz0;            // global (b,h,block) index

    int bb = 0, hh = 0, jb = 0;
    if constexpr (MODE == M_P || MODE == M_INTRA || MODE == M_KVT) {
        bb = bz >> 8; hh = (bz >> 4) & 15; jb = bz & 15;
    }

    if constexpr (MODE == M_P) {
        // tile fully above the (block-local) diagonal -> all zeros, skip GEMM
        if (tn > tm) {
            u16* C = (u16*)Cv + (size_t)bzl * 65536 + tm * 128 * 256 + tn * 128;
            uint4 z = make_uint4(0u, 0u, 0u, 0u);
            #pragma unroll
            for (int i = 0; i < 8; i++) {
                int f = tid + 256 * i;
                int row = f >> 4, c8 = (f & 15) * 8;
                *(uint4*)&C[row * 256 + c8] = z;
            }
            return;
        }
    }

    __shared__ u16 smem[8192];            // As/Bs staging, 16,384 B
    u16 (*As)[32] = (u16(*)[32])smem;
    u16 (*Bs)[32] = (u16(*)[32])(smem + 4096);

    const int lane = tid & 63, wv = tid >> 6;
    const int wm = (wv & 1) * 64, wn = (wv >> 1) * 64;
    const int quad = lane >> 4, cl = lane & 15;
    const int lr = lane >> 2;            // 0..15: row within 16-row chunk
    const int lc = (lane & 3) * 8;       // 0/8/16/24: col elem offset
    u16* lA = &As[wv * 32][0];           // wave-uniform LDS bases
    u16* lB = &Bs[wv * 32][0];

    f32x4 acc[4][4];
    const f32x4 zero = {0.f, 0.f, 0.f, 0.f};
    #pragma unroll
    for (int mi = 0; mi < 4; mi++)
        #pragma unroll
        for (int ni = 0; ni < 4; ni++) acc[mi][ni] = zero;

    #pragma unroll
    for (int ph = 0; ph < NPH; ph++) {
        const u16* Ab; const u16* Bb; int lda, ldb, kmax;
        if constexpr (MODE == M_QKV || MODE == M_OUT) {
            Ab = A; lda = HID; Bb = Bm; ldb = HID; kmax = 2048;
        } else if constexpr (MODE == M_P) {
            const size_t o = ((size_t)(bb * SEQ + jb * 256)) * HID + hh * 128;
            Ab = A + o; lda = HID;                     // q rows
            Bb = Bm + o; ldb = HID;                    // k rows
            kmax = 128;
        } else if constexpr (MODE == M_KVT) {
            Ab = A + (size_t)bz * 32768; lda = 256;    // vT
            Bb = Bm + (size_t)bz * 32768; ldb = 256;   // kTs
            kmax = 256;
        } else { // M_INTRA
            if (ph == 0) {  // inter: q @ S^T
                Ab = A + ((size_t)(bb * SEQ + jb * 256)) * HID + hh * 128; lda = HID;
                Bb = Bm + (size_t)bz * 16384; ldb = 128;   // S^T bf16
                kmax = 128;
            } else {        // intra: P @ v
                Ab = (const u16*)aux + (size_t)bzl * 65536; lda = 256;   // P
                Bb = (const u16*)aux2 + (size_t)bz * 32768; ldb = 256;   // vT
                kmax = (tm == 0) ? 128 : 256;          // P upper half is 0
            }
        }
        const u16* gA = Ab + (size_t)(tm * 128 + wv * 32 + lr) * lda + lc;
        const u16* gB = Bb + (size_t)(tn * 128 + wv * 32 + lr) * ldb + lc;

        for (int k0 = 0; k0 < kmax; k0 += 32) {
            __syncthreads();
            gld16(gA + k0,                    lA);
            gld16(gA + k0 + (size_t)16 * lda, lA + 16 * 32);
            gld16(gB + k0,                    lB);
            gld16(gB + k0 + (size_t)16 * ldb, lB + 16 * 32);
            __syncthreads();
            const int ko = quad * 8;
            bf16x8 af[4], bfv[4];
            #pragma unroll
            for (int mi = 0; mi < 4; mi++) af[mi] = *(const bf16x8*)&As[wm + mi * 16 + cl][ko];
            #pragma unroll
            for (int ni = 0; ni < 4; ni++) bfv[ni] = *(const bf16x8*)&Bs[wn + ni * 16 + cl][ko];
            #pragma unroll
            for (int mi = 0; mi < 4; mi++)
                #pragma unroll
                for (int ni = 0; ni < 4; ni++)
                    acc[mi][ni] = __builtin_amdgcn_mfma_f32_16x16x32_bf16(af[mi], bfv[ni], acc[mi][ni], 0, 0, 0);
        }

        if constexpr (MODE == M_INTRA) {
            if (ph == 0) {   // scale inter part by q_decay(row)
                const float s_ = slope[hh];
                #pragma unroll
                for (int mi = 0; mi < 4; mi++)
                    #pragma unroll
                    for (int r = 0; r < 4; r++) {
                        const int m = tm * 128 + wm + mi * 16 + quad * 4 + r;
                        const float qd = __expf(-s_ * (float)(m + 1));
                        #pragma unroll
                        for (int ni = 0; ni < 4; ni++) acc[mi][ni][r] *= qd;
                    }
            }
        }
    }

    float sl = 0.f;
    if constexpr (MODE == M_P) sl = slope[hh];

    #pragma unroll
    for (int mi = 0; mi < 4; mi++) {
        #pragma unroll
        for (int ni = 0; ni < 4; ni++) {
            const f32x4 v = acc[mi][ni];
            #pragma unroll
            for (int r = 0; r < 4; r++) {
                const int m = tm * 128 + wm + mi * 16 + quad * 4 + r;  // C row (A index)
                const int n = tn * 128 + wn + ni * 16 + cl;            // C col (B index)
                const float x = v[r];
                if constexpr (MODE == M_P) {
                    const int d = m - n;
                    ((u16*)Cv)[(size_t)bzl * 65536 + m * 256 + n] =
                        f2bf(d >= 0 ? x * __expf(-sl * (float)d) : 0.f);
                } else if constexpr (MODE == M_INTRA) {
                    ((u16*)Cv)[((size_t)(bb * SEQ + jb * 256 + m)) * HID + hh * 128 + n] = f2bf(x);
                } else if constexpr (MODE == M_KVT) {
                    ((float*)Cv)[(size_t)bz * 16384 + m * 128 + n] = x;
                } else { // M_OUT
                    ((float*)Cv)[(size_t)m * HID + n] = x;
                }
            }
        }
    }
}

// ---------------------------------------------------------------------------
// Per (b,h,block): kTs[d][m] = k[m][d] * exp(-s*(255-m))  (vectorized stores)
// ---------------------------------------------------------------------------
__global__ __launch_bounds__(256) void transpose_k(const u16* __restrict__ kb,
                                                   u16* __restrict__ kTs,
                                                   const float* __restrict__ slope) {
    __shared__ u16 t[128][137];   // pad 137: transposed-read lanes land 2-way max
    const int bz = blockIdx.x;
    const int bb = bz >> 8, hh = (bz >> 4) & 15, jb = bz & 15;
    const int tid = threadIdx.x;
    const float s_ = slope[hh];
    const u16* src = kb + ((size_t)(bb * SEQ + jb * 256)) * HID + hh * 128;
    u16* dst = kTs + (size_t)bz * 32768;

    for (int half = 0; half < 2; half++) {
        #pragma unroll
        for (int i = 0; i < 8; i++) {
            const int flat = tid + 256 * i;
            const int row = flat >> 4, c8 = (flat & 15) * 8;
            *(uint4*)&t[row][c8] = *(const uint4*)&src[(size_t)(half * 128 + row) * HID + c8];
        }
        __syncthreads();
        #pragma unroll
        for (int i = 0; i < 8; i++) {
            const int flat = tid + 256 * i;
            const int d = flat >> 4, mc = (flat & 15) * 8;
            u16 p[8];
            #pragma unroll
            for (int j = 0; j < 8; j++) {
                const int m = half * 128 + mc + j;
                p[j] = f2bf(bf2f(t[mc + j][d]) * __expf(-s_ * (float)(255 - m)));
            }
            uint4 pk;
            pk.x = (unsigned)p[0] | ((unsigned)p[1] << 16);
            pk.y = (unsigned)p[2] | ((unsigned)p[3] << 16);
            pk.z = (unsigned)p[4] | ((unsigned)p[5] << 16);
            pk.w = (unsigned)p[6] | ((unsigned)p[7] << 16);
            *(uint4*)&dst[(size_t)d * 256 + half * 128 + mc] = pk;
        }
        __syncthreads();
    }
}

// ---------------------------------------------------------------------------
// S_0 = 0; write S_j^T (bf16); S_{j+1} = e^{-256 s} S_j + KV_j
// 512 WGs: (b,h) x 16 column-chunks; serial only over j.
// ---------------------------------------------------------------------------
__global__ __launch_bounds__(256) void scan_kv(const float* __restrict__ KVT,
                                               u16* __restrict__ ST,
                                               const float* __restrict__ slope) {
    const int bh = blockIdx.x >> 4, ch = blockIdx.x & 15;
    const int off = ch * 1024 + threadIdx.x * 4;
    const float bd = __expf(-256.f * slope[bh & 15]);
    float4 st = {0.f, 0.f, 0.f, 0.f};
    for (int j = 0; j < 16; j++) {
        const size_t base = ((size_t)(bh * 16 + j)) * 16384 + off;
        uint2 o;
        o.x = (unsigned)f2bf(st.x) | ((unsigned)f2bf(st.y) << 16);
        o.y = (unsigned)f2bf(st.z) | ((unsigned)f2bf(st.w) << 16);
        *(uint2*)&ST[base] = o;
        const float4 kv = *(const float4*)&KVT[base];
        st.x = bd * st.x + kv.x;
        st.y = bd * st.y + kv.y;
        st.z = bd * st.z + kv.z;
        st.w = bd * st.w + kv.w;
    }
}

// ---------------------------------------------------------------------------
// y = gate * (attn * rsqrt(mean(attn^2)+eps)) * norm_w   (one WG per row)
// ---------------------------------------------------------------------------
__global__ __launch_bounds__(256) void rmsnorm_gate(const u16* __restrict__ attn,
                                                    const u16* __restrict__ gate,
                                                    const float* __restrict__ nw,
                                                    u16* __restrict__ y) {
    const int r = blockIdx.x, tid = threadIdx.x;
    const size_t base = (size_t)r * HID + tid * 8;
    const uint4 a = *(const uint4*)&attn[base];
    float x[8];
    x[0] = bf2f(a.x & 0xffff); x[1] = bf2f(a.x >> 16);
    x[2] = bf2f(a.y & 0xffff); x[3] = bf2f(a.y >> 16);
    x[4] = bf2f(a.z & 0xffff); x[5] = bf2f(a.z >> 16);
    x[6] = bf2f(a.w & 0xffff); x[7] = bf2f(a.w >> 16);
    float s = 0.f;
    #pragma unroll
    for (int i = 0; i < 8; i++) s += x[i] * x[i];
    #pragma unroll
    for (int off = 32; off > 0; off >>= 1) s += __shfl_down(s, off);
    __shared__ float red[4];
    if ((tid & 63) == 0) red[tid >> 6] = s;
    __syncthreads();
    const float tot = red[0] + red[1] + red[2] + red[3];
    const float sc = rsqrtf(tot * (1.f / 2048.f) + 1e-6f);
    const uint4 g = *(const uint4*)&gate[base];
    float gv[8];
    gv[0] = bf2f(g.x & 0xffff); gv[1] = bf2f(g.x >> 16);
    gv[2] = bf2f(g.y & 0xffff); gv[3] = bf2f(g.y >> 16);
    gv[4] = bf2f(g.z & 0xffff); gv[5] = bf2f(g.z >> 16);
    gv[6] = bf2f(g.w & 0xffff); gv[7] = bf2f(g.w >> 16);
    const float4 w0 = *(const float4*)&nw[tid * 8];
    const float4 w1 = *(const float4*)&nw[tid * 8 + 4];
    const float wv[8] = {w0.x, w0.y, w0.z, w0.w, w1.x, w1.y, w1.z, w1.w};
    u16 o[8];
    #pragma unroll
    for (int i = 0; i < 8; i++) o[i] = f2bf(gv[i] * x[i] * sc * wv[i]);
    uint4 ov;
    ov.x = (unsigned)o[0] | ((unsigned)o[1] << 16);
    ov.y = (unsigned)o[2] | ((unsigned)o[3] << 16);
    ov.z = (unsigned)o[4] | ((unsigned)o[5] << 16);
    ov.w = (unsigned)o[6] | ((unsigned)o[7] << 16);
    *(uint4*)&y[base] = ov;
}

// ---------------------------------------------------------------------------
extern "C" void kernel_launch(void* const* d_in, const int* in_sizes, int n_in,
                              void* d_out, int out_size, void* d_ws, size_t ws_size,
                              hipStream_t stream) {
    const float* hidden = (const float*)d_in[0];
    const float* slope  = (const float*)d_in[1];
    const float* w_qkv  = (const float*)d_in[2];
    const float* w_gate = (const float*)d_in[3];
    const float* w_out  = (const float*)d_in[4];
    const float* norm_w = (const float*)d_in[5];
    float* out = (float*)d_out;

    // 7 slots x 33,554,432 B = 234,881,024 B total
    char* w = (char*)d_ws;
    u16* qb   = (u16*)(w);                 // S0: q                 [QKV .. intra#2]
    u16* kb   = (u16*)(w +  33554432);     // S1: k                 [QKV .. P#2]
    u16* kTs  = (u16*)(w +  67108864);     // S2: kTs               [transpose .. KVT]
    u16* hid_bf = (u16*)(w + 100663296);   // S3: hidden bf16       [cast .. QKV]
    u16* vT   = (u16*)(w + 134217728);     // S4: vT (via QKV)      [QKV .. intra#2]
    u16* gate = (u16*)(w + 167772160);     // S5: gate (via QKV)    [QKV .. rms]
    u16* wqkv_bf  = (u16*)(w + 201326592); // S6: w_qkv bf16 25.17M [cast .. QKV]
    u16* wgate_bf = (u16*)(w + 201326592 + 25165824); // S6 tail 8.39M, contiguous
    // aliases (disjoint lifetimes):
    float* KVT  = (float*)hid_bf;          // S3: KV^T fp32         [KVT .. scan]
    u16*   ST   = kTs;                     // S2: S^T bf16 16.8M    [scan .. intra#2]
    u16*   P    = hid_bf;                  // S3: P half            [P#1 .. intra#2]
    u16*   wout_bf = kb;                   // S1: w_out bf16        [cast .. OUT]
    u16*   attn = wqkv_bf;                 // S6: attn              [intra#1 .. rms]
    u16*   y    = kTs;                     // S2: y                 [rms .. OUT]

    static bool s_attr = false;
    if (!s_attr) {
        (void)hipFuncSetAttribute((const void*)gemm256<0>,
                                  hipFuncAttributeMaxDynamicSharedMemorySize, 65536);
        (void)hipFuncSetAttribute((const void*)gemm256<1>,
                                  hipFuncAttributeMaxDynamicSharedMemorySize, 65536);
        s_attr = true;
    }

    castk<<<16384, 256, 0, stream>>>(hidden, hid_bf);
    castk<<<12288, 256, 0, stream>>>(w_qkv,  wqkv_bf);
    castk<<< 4096, 256, 0, stream>>>(w_gate, wgate_bf);

    // fused qkv+gate: B = [w_qkv ; w_gate] (8192 x 2048 contiguous)
    gemm256<0><<<dim3(1024), dim3(512), 65536, stream>>>(hid_bf, wqkv_bf, qb, vT, gate);
    transpose_k     <<<512,             256, 0, stream>>>(kb, kTs, slope);
    gemm_nt<M_KVT ><<<dim3(1, 1, 512),  256, 0, stream>>>(vT, kTs, KVT, slope, 0, nullptr, nullptr);
    scan_kv         <<<512,             256, 0, stream>>>(KVT, ST, slope);
    gemm_nt<M_P   ><<<dim3(2, 2, 256),  256, 0, stream>>>(qb, kb, P, slope, 0, nullptr, nullptr);
    gemm_nt<M_INTRA><<<dim3(2, 1, 256), 256, 0, stream>>>(qb, ST, attn, slope, 0, P, vT);
    gemm_nt<M_P   ><<<dim3(2, 2, 256),  256, 0, stream>>>(qb, kb, P, slope, 256, nullptr, nullptr);
    gemm_nt<M_INTRA><<<dim3(2, 1, 256), 256, 0, stream>>>(qb, ST, attn, slope, 256, P, vT);
    castk<<< 4096, 256, 0, stream>>>(w_out, wout_bf);
    rmsnorm_gate    <<<8192,            256, 0, stream>>>(attn, gate, norm_w, y);
    gemm256<1><<<dim3(256), dim3(512), 65536, stream>>>(y, wout_bf, (void*)out, nullptr, nullptr);
}

// Round 10
// 504.034 us; speedup vs baseline: 6.9647x; 6.9647x over previous
//
#include <hip/hip_runtime.h>

// ---------------------------------------------------------------------------
// MiniMax-M1 Lightning Attention forward, MI355X / gfx950.
//   0. cast fp32->bf16: hidden, w_qkv(+w_gate contiguous)
//   1. fused qkv+gate via 128x128 BK=64 lockstep GEMM, 4 waves, 64KB LDS
//      -> 2 INDEPENDENT blocks/CU whose phases interleave (MFMA fills the
//      other block's read/drain windows).  R7-proven schedule & swizzle.
//   2. transpose_k: kTs[d][m] = silu_k[m][d] * exp(-s*(255-m))
//   3. KVT_j = vT @ kTs^T  (= KV_j^T, fp32)
//   4. scan: S_{j+1} = e^{-256 s} S_j + KV_j ; store S_j^T bf16  [512 WGs]
//   5. P = (q k^T) * diag_decay  per block   [2 half-launches, 1-slot P buffer]
//   6. intra+inter fused: acc = q @ S^T; acc *= q_decay(row); acc += P @ v
//   7. y = gate * rmsnorm(attn) * norm_w
//   8. out = y @ w_out^T via same 128 GEMM [fp32 -> d_out]
// Workspace: 7 slots x 33,554,432 B = 234,881,024 B peak (proven to fit).
// ---------------------------------------------------------------------------

typedef unsigned short u16;
typedef __bf16 bf16x8 __attribute__((ext_vector_type(8)));
typedef float f32x4 __attribute__((ext_vector_type(4)));

#define SEQ 4096
#define HID 2048

__device__ __forceinline__ u16 f2bf(float f) {
    union { float f; unsigned u; } v; v.f = f;
    unsigned r = v.u + 0x7fffu + ((v.u >> 16) & 1u);   // round-to-nearest-even
    return (u16)(r >> 16);
}
__device__ __forceinline__ float bf2f(u16 u) {
    union { unsigned u; float f; } v; v.u = ((unsigned)u) << 16; return v.f;
}

// async global->LDS, 16B per lane; lds dest must be wave-uniform base (+lane*16)
typedef __attribute__((address_space(1))) unsigned char gas_u8;
typedef __attribute__((address_space(3))) unsigned char las_u8;
__device__ __forceinline__ void gld16(const void* g, void* l) {
    __builtin_amdgcn_global_load_lds((gas_u8*)g, (las_u8*)l, 16, 0, 0);
}

// ---------------------------------------------------------------------------
// fp32 -> bf16 cast, 4 elems/thread, exact grids (n % 1024 == 0)
// ---------------------------------------------------------------------------
__global__ __launch_bounds__(256) void castk(const float* __restrict__ in,
                                             u16* __restrict__ out) {
    const size_t i = (size_t)blockIdx.x * 256 + threadIdx.x;
    const float4 f = *(const float4*)&in[i * 4];
    uint2 o;
    o.x = (unsigned)f2bf(f.x) | ((unsigned)f2bf(f.y) << 16);
    o.y = (unsigned)f2bf(f.z) | ((unsigned)f2bf(f.w) << 16);
    *(uint2*)&out[i * 4] = o;
}

// ---------------------------------------------------------------------------
// 128x128-tile BK=64 lockstep pipelined NT GEMM (C = A[Mx2048] * B[Nx2048]^T).
// 256 threads = 4 waves (2x2), each wave 64x64 out (4x4 16x16 frags).
// LDS 64 KiB: 2 K-tile buffers x (A 128x64 + B 128x64) bf16 -> 2 blocks/CU;
// the two blocks are NOT barrier-synced, so one block's MFMA phases overlap
// the other's read/stage/drain windows (implicit wave-level overlap, m114).
// Swizzle: rows are 128B; physical 16B chunk = logical ^ (row&7), applied as
// inverse-swizzled GLOBAL source (linear global_load_lds dest) + swizzled
// ds_read.  Counted vmcnt(6) once per K-tile (STG unit = 2 gld16, ledger
// identical to the proven 256-tile schedule); lgkm(4) stagger on the 8-read
// phase; setprio(1) around each 8-MFMA burst.
// __launch_bounds__(256,2): reg cap 256 under either arg interpretation
// (R9 lesson: (512,4) forced a 64-VGPR cap -> total spill).
// MODE 0: fused QKV+gate epilogue; MODE 1: f32 out.
// ---------------------------------------------------------------------------
template <int MODE>
__global__ __launch_bounds__(256, 2) void gemm256(const u16* __restrict__ A,
                                                  const u16* __restrict__ Bm,
                                                  void* __restrict__ Cv,
                                                  void* __restrict__ aux,
                                                  void* __restrict__ aux2) {
    constexpr int NT = 32;                        // K tiles (2048 / 64)
    extern __shared__ u16 smem[];                 // [2][A 8192 | B 8192] elems

    // XCD swizzle: 8 XCDs; per-XCD 8 tile-rows x all cols (A panels L2-resident)
    const int bid = blockIdx.x;
    const int xcd = bid & 7, l = bid >> 3;
    const int tm = xcd * 8 + (l & 7);             // 0..63
    const int tn = l >> 3;                        // MODE0: 0..63, MODE1: 0..15

    const int tid  = threadIdx.x;
    const int lane = tid & 63, wv = tid >> 6;     // 4 waves, 2x2
    const int quad = lane >> 4, cl = lane & 15;
    const int wm = (wv & 1) * 64, wn = (wv >> 1) * 64;

    // staging: thread t covers row tid>>3 (0..31 per issue), 16B chunk tid&7,
    // global chunk pre-XORed so linear LDS dest holds the swizzled layout
    const int srw  = tid >> 3;
    const int colo = ((tid & 7) ^ (srw & 7)) * 8;
    const u16* gA0 = A  + (size_t)(tm * 128 + srw) * HID + colo;
    const u16* gB0 = Bm + (size_t)(tn * 128 + srw) * HID + colo;

    // ds_read swizzle: LDS (row, slot) holds global chunk slot^(row&7); frag
    // row base is 16-aligned so row&7 == cl&7
    const int x0 = ((quad       ^ (cl & 7)) * 8);
    const int x1 = (((4 + quad) ^ (cl & 7)) * 8);

    f32x4 acc[4][4];
    const f32x4 zero = {0.f, 0.f, 0.f, 0.f};
    #pragma unroll
    for (int a = 0; a < 4; a++)
        #pragma unroll
        for (int b = 0; b < 4; b++) acc[a][b] = zero;

    bf16x8 af[4], b0v[4], b1v[4];

    auto STG = [&](int kt, int mat, int hh) {   // stage one 64x64 half-tile
        const u16* g = (mat ? gB0 : gA0) + (size_t)(hh * 64) * HID + kt * 64;
        u16* lp = smem + (kt & 1) * 16384 + mat * 8192 + hh * 4096 + wv * 512;
        gld16(g, lp);
        gld16(g + (size_t)32 * HID, lp + 2048);
    };
    auto LDA = [&](int qm, int ab) {            // 2 m-frags x 2 k-halves
        #pragma unroll
        for (int mi = 0; mi < 2; mi++) {
            const int rr = (wm + qm * 32 + mi * 16 + cl) * 64 + ab;
            af[mi * 2 + 0] = *(const bf16x8*)&smem[rr + x0];
            af[mi * 2 + 1] = *(const bf16x8*)&smem[rr + x1];
        }
    };
    auto LDB = [&](bf16x8* d, int qn, int bb2) {
        #pragma unroll
        for (int ni = 0; ni < 2; ni++) {
            const int rr = (wn + qn * 32 + ni * 16 + cl) * 64 + bb2;
            d[ni * 2 + 0] = *(const bf16x8*)&smem[rr + x0];
            d[ni * 2 + 1] = *(const bf16x8*)&smem[rr + x1];
        }
    };
    auto MM = [&](int qm, int qn, const bf16x8* bv) {
        #pragma unroll
        for (int mi = 0; mi < 2; mi++)
            #pragma unroll
            for (int ni = 0; ni < 2; ni++) {
                f32x4 c = acc[qm * 2 + mi][qn * 2 + ni];
                c = __builtin_amdgcn_mfma_f32_16x16x32_bf16(af[mi * 2 + 0], bv[ni * 2 + 0], c, 0, 0, 0);
                c = __builtin_amdgcn_mfma_f32_16x16x32_bf16(af[mi * 2 + 1], bv[ni * 2 + 1], c, 0, 0, 0);
                acc[qm * 2 + mi][qn * 2 + ni] = c;
            }
    };

    // prologue: issue stream per tile = B.lo, B.hi, A.lo, A.hi (2 loads each)
    STG(0, 1, 0); STG(0, 1, 1); STG(0, 0, 0); STG(0, 0, 1);
    STG(1, 1, 0); STG(1, 1, 1); STG(1, 0, 0);
    asm volatile("s_waitcnt vmcnt(6)" ::: "memory");   // tile 0 resident (8 drained)
    __builtin_amdgcn_s_barrier();

    #pragma unroll 2
    for (int t = 0; t < NT; ++t) {
        const int ab  = (t & 1) * 16384;
        const int bb2 = ab + 8192;
        // phase 0: C(0,0); issue (t+1).A.hi
        LDA(0, ab); LDB(b0v, 0, bb2);
        if (t + 1 < NT) STG(t + 1, 0, 1);
        asm volatile("s_waitcnt lgkmcnt(4)" ::: "memory");  // stagger drain
        __builtin_amdgcn_s_barrier();
        asm volatile("s_waitcnt lgkmcnt(0)" ::: "memory");
        __builtin_amdgcn_s_setprio(1); MM(0, 0, b0v); __builtin_amdgcn_s_setprio(0);
        __builtin_amdgcn_s_barrier();
        // phase 1: C(0,1); issue (t+2).B.lo  [B dead after this phase]
        LDB(b1v, 1, bb2);
        if (t + 2 < NT) STG(t + 2, 1, 0);
        __builtin_amdgcn_s_barrier();
        asm volatile("s_waitcnt lgkmcnt(0)" ::: "memory");
        __builtin_amdgcn_s_setprio(1); MM(0, 1, b1v); __builtin_amdgcn_s_setprio(0);
        __builtin_amdgcn_s_barrier();
        // phase 2: C(1,1); issue (t+2).B.hi
        LDA(1, ab);
        if (t + 2 < NT) STG(t + 2, 1, 1);
        __builtin_amdgcn_s_barrier();
        asm volatile("s_waitcnt lgkmcnt(0)" ::: "memory");
        __builtin_amdgcn_s_setprio(1); MM(1, 1, b1v); __builtin_amdgcn_s_setprio(0);
        __builtin_amdgcn_s_barrier();
        // phase 3: C(1,0); issue (t+2).A.lo; boundary wait: keep newest 6
        // loads = (t+2).{B.lo,B.hi,A.lo} -> tile t+1 fully landed
        if (t + 2 < NT) {
            STG(t + 2, 0, 0);
            asm volatile("s_waitcnt vmcnt(6)" ::: "memory");
        } else {
            asm volatile("s_waitcnt vmcnt(0)" ::: "memory");
        }
        __builtin_amdgcn_s_barrier();
        __builtin_amdgcn_s_setprio(1); MM(1, 0, b0v); __builtin_amdgcn_s_setprio(0);
        __builtin_amdgcn_s_barrier();
    }

    // epilogue (baseline-proven 128^2 geometry):
    //   m = tm*128 + wm + mi*16 + quad*4 + r ; n-within = wn + ni*16 + cl
    if constexpr (MODE == 0) {
        // tn 0-15: q | 16-31: k | 32-47: v (direct transposed) | 48-63: gate
        const int which = tn >> 4, hd = tn & 15;
        if (which == 2) {
            // vT[bz][d][m]: lane holds 4 consecutive m at fixed d -> uint2
            const int bbq = tm >> 5, jbq = (tm >> 1) & 15, half = tm & 1;
            const size_t bz = (size_t)(bbq * 256 + hd * 16 + jbq);
            u16* tdst = (u16*)aux + bz * 32768 + half * 128;
            const int mloc = wm + (quad << 2);
            #pragma unroll
            for (int mi = 0; mi < 4; mi++)
                #pragma unroll
                for (int ni = 0; ni < 4; ni++) {
                    const int d = wn + ni * 16 + cl;
                    u16 p[4];
                    #pragma unroll
                    for (int r = 0; r < 4; r++) {
                        const float x = acc[mi][ni][r];
                        p[r] = f2bf(x / (1.f + __expf(-x)));
                    }
                    uint2 pk;
                    pk.x = (unsigned)p[0] | ((unsigned)p[1] << 16);
                    pk.y = (unsigned)p[2] | ((unsigned)p[3] << 16);
                    *(uint2*)&tdst[(size_t)d * 256 + mloc + mi * 16] = pk;
                }
            return;
        }
        u16* dst = (which == 0) ? (u16*)Cv
                 : (which == 1) ? (u16*)Cv + (size_t)16777216   // k slot (S1)
                                : (u16*)aux2;                   // gate slot
        #pragma unroll
        for (int mi = 0; mi < 4; mi++)
            #pragma unroll
            for (int ni = 0; ni < 4; ni++)
                #pragma unroll
                for (int r = 0; r < 4; r++) {
                    const int m = tm * 128 + wm + mi * 16 + quad * 4 + r;
                    const int n = hd * 128 + wn + ni * 16 + cl;
                    const float x = acc[mi][ni][r];
                    const float v = (which == 3) ? 1.f / (1.f + __expf(-x))
                                                 : x / (1.f + __expf(-x));
                    dst[(size_t)m * HID + n] = f2bf(v);
                }
        return;
    } else {
        float* C = (float*)Cv;
        #pragma unroll
        for (int mi = 0; mi < 4; mi++)
            #pragma unroll
            for (int ni = 0; ni < 4; ni++)
                #pragma unroll
                for (int r = 0; r < 4; r++) {
                    const int m = tm * 128 + wm + mi * 16 + quad * 4 + r;
                    const int n = tn * 128 + wn + ni * 16 + cl;
                    C[(size_t)m * HID + n] = acc[mi][ni][r];
                }
    }
}

// ---------------------------------------------------------------------------
// Generic 128x128-tile NT GEMM for the small per-(b,h,block) ops.
// ---------------------------------------------------------------------------
#define M_QKV   0
#define M_P     2
#define M_INTRA 3
#define M_KVT   4
#define M_OUT   6

template <int MODE>
__global__ __launch_bounds__(256) void gemm_nt(const u16* __restrict__ A,
                                               const u16* __restrict__ Bm,
                                               void* __restrict__ Cv,
                                               const float* __restrict__ slope,
                                               int bz0,
                                               void* __restrict__ aux,
                                               void* __restrict__ aux2) {
    constexpr int NPH = (MODE == M_INTRA) ? 2 : 1;
    const int tid = threadIdx.x;
    const int tm = blockIdx.x, tn = blockIdx.y;
    const int bzl = blockIdx.z;           // local z (P buffer index)
    const int bz  = bzl + bz0;            // global (b,h,block) index

    int bb = 0, hh = 0, jb = 0;
    if constexpr (MODE == M_P || MODE == M_INTRA || MODE == M_KVT) {
        bb = bz >> 8; hh = (bz >> 4) & 15; jb = bz & 15;
    }

    if constexpr (MODE == M_P) {
        // tile fully above the (block-local) diagonal -> all zeros, skip GEMM
        if (tn > tm) {
            u16* C = (u16*)Cv + (size_t)bzl * 65536 + tm * 128 * 256 + tn * 128;
            uint4 z = make_uint4(0u, 0u, 0u, 0u);
            #pragma unroll
            for (int i = 0; i < 8; i++) {
                int f = tid + 256 * i;
                int row = f >> 4, c8 = (f & 15) * 8;
                *(uint4*)&C[row * 256 + c8] = z;
            }
            return;
        }
    }

    __shared__ u16 smem[8192];            // As/Bs staging, 16,384 B
    u16 (*As)[32] = (u16(*)[32])smem;
    u16 (*Bs)[32] = (u16(*)[32])(smem + 4096);

    const int lane = tid & 63, wv = tid >> 6;
    const int wm = (wv & 1) * 64, wn = (wv >> 1) * 64;
    const int quad = lane >> 4, cl = lane & 15;
    const int lr = lane >> 2;            // 0..15: row within 16-row chunk
    const int lc = (lane & 3) * 8;       // 0/8/16/24: col elem offset
    u16* lA = &As[wv * 32][0];           // wave-uniform LDS bases
    u16* lB = &Bs[wv * 32][0];

    f32x4 acc[4][4];
    const f32x4 zero = {0.f, 0.f, 0.f, 0.f};
    #pragma unroll
    for (int mi = 0; mi < 4; mi++)
        #pragma unroll
        for (int ni = 0; ni < 4; ni++) acc[mi][ni] = zero;

    #pragma unroll
    for (int ph = 0; ph < NPH; ph++) {
        const u16* Ab; const u16* Bb; int lda, ldb, kmax;
        if constexpr (MODE == M_QKV || MODE == M_OUT) {
            Ab = A; lda = HID; Bb = Bm; ldb = HID; kmax = 2048;
        } else if constexpr (MODE == M_P) {
            const size_t o = ((size_t)(bb * SEQ + jb * 256)) * HID + hh * 128;
            Ab = A + o; lda = HID;                     // q rows
            Bb = Bm + o; ldb = HID;                    // k rows
            kmax = 128;
        } else if constexpr (MODE == M_KVT) {
            Ab = A + (size_t)bz * 32768; lda = 256;    // vT
            Bb = Bm + (size_t)bz * 32768; ldb = 256;   // kTs
            kmax = 256;
        } else { // M_INTRA
            if (ph == 0) {  // inter: q @ S^T
                Ab = A + ((size_t)(bb * SEQ + jb * 256)) * HID + hh * 128; lda = HID;
                Bb = Bm + (size_t)bz * 16384; ldb = 128;   // S^T bf16
                kmax = 128;
            } else {        // intra: P @ v
                Ab = (const u16*)aux + (size_t)bzl * 65536; lda = 256;   // P
                Bb = (const u16*)aux2 + (size_t)bz * 32768; ldb = 256;   // vT
                kmax = (tm == 0) ? 128 : 256;          // P upper half is 0
            }
        }
        const u16* gA = Ab + (size_t)(tm * 128 + wv * 32 + lr) * lda + lc;
        const u16* gB = Bb + (size_t)(tn * 128 + wv * 32 + lr) * ldb + lc;

        for (int k0 = 0; k0 < kmax; k0 += 32) {
            __syncthreads();
            gld16(gA + k0,                    lA);
            gld16(gA + k0 + (size_t)16 * lda, lA + 16 * 32);
            gld16(gB + k0,                    lB);
            gld16(gB + k0 + (size_t)16 * ldb, lB + 16 * 32);
            __syncthreads();
            const int ko = quad * 8;
            bf16x8 af[4], bfv[4];
            #pragma unroll
            for (int mi = 0; mi < 4; mi++) af[mi] = *(const bf16x8*)&As[wm + mi * 16 + cl][ko];
            #pragma unroll
            for (int ni = 0; ni < 4; ni++) bfv[ni] = *(const bf16x8*)&Bs[wn + ni * 16 + cl][ko];
            #pragma unroll
            for (int mi = 0; mi < 4; mi++)
                #pragma unroll
                for (int ni = 0; ni < 4; ni++)
                    acc[mi][ni] = __builtin_amdgcn_mfma_f32_16x16x32_bf16(af[mi], bfv[ni], acc[mi][ni], 0, 0, 0);
        }

        if constexpr (MODE == M_INTRA) {
            if (ph == 0) {   // scale inter part by q_decay(row)
                const float s_ = slope[hh];
                #pragma unroll
                for (int mi = 0; mi < 4; mi++)
                    #pragma unroll
                    for (int r = 0; r < 4; r++) {
                        const int m = tm * 128 + wm + mi * 16 + quad * 4 + r;
                        const float qd = __expf(-s_ * (float)(m + 1));
                        #pragma unroll
                        for (int ni = 0; ni < 4; ni++) acc[mi][ni][r] *= qd;
                    }
            }
        }
    }

    float sl = 0.f;
    if constexpr (MODE == M_P) sl = slope[hh];

    #pragma unroll
    for (int mi = 0; mi < 4; mi++) {
        #pragma unroll
        for (int ni = 0; ni < 4; ni++) {
            const f32x4 v = acc[mi][ni];
            #pragma unroll
            for (int r = 0; r < 4; r++) {
                const int m = tm * 128 + wm + mi * 16 + quad * 4 + r;  // C row (A index)
                const int n = tn * 128 + wn + ni * 16 + cl;            // C col (B index)
                const float x = v[r];
                if constexpr (MODE == M_P) {
                    const int d = m - n;
                    ((u16*)Cv)[(size_t)bzl * 65536 + m * 256 + n] =
                        f2bf(d >= 0 ? x * __expf(-sl * (float)d) : 0.f);
                } else if constexpr (MODE == M_INTRA) {
                    ((u16*)Cv)[((size_t)(bb * SEQ + jb * 256 + m)) * HID + hh * 128 + n] = f2bf(x);
                } else if constexpr (MODE == M_KVT) {
                    ((float*)Cv)[(size_t)bz * 16384 + m * 128 + n] = x;
                } else { // M_OUT
                    ((float*)Cv)[(size_t)m * HID + n] = x;
                }
            }
        }
    }
}

// ---------------------------------------------------------------------------
// Per (b,h,block): kTs[d][m] = k[m][d] * exp(-s*(255-m))  (vectorized stores)
// ---------------------------------------------------------------------------
__global__ __launch_bounds__(256) void transpose_k(const u16* __restrict__ kb,
                                                   u16* __restrict__ kTs,
                                                   const float* __restrict__ slope) {
    __shared__ u16 t[128][137];   // pad 137: transposed-read lanes land 2-way max
    const int bz = blockIdx.x;
    const int bb = bz >> 8, hh = (bz >> 4) & 15, jb = bz & 15;
    const int tid = threadIdx.x;
    const float s_ = slope[hh];
    const u16* src = kb + ((size_t)(bb * SEQ + jb * 256)) * HID + hh * 128;
    u16* dst = kTs + (size_t)bz * 32768;

    for (int half = 0; half < 2; half++) {
        #pragma unroll
        for (int i = 0; i < 8; i++) {
            const int flat = tid + 256 * i;
            const int row = flat >> 4, c8 = (flat & 15) * 8;
            *(uint4*)&t[row][c8] = *(const uint4*)&src[(size_t)(half * 128 + row) * HID + c8];
        }
        __syncthreads();
        #pragma unroll
        for (int i = 0; i < 8; i++) {
            const int flat = tid + 256 * i;
            const int d = flat >> 4, mc = (flat & 15) * 8;
            u16 p[8];
            #pragma unroll
            for (int j = 0; j < 8; j++) {
                const int m = half * 128 + mc + j;
                p[j] = f2bf(bf2f(t[mc + j][d]) * __expf(-s_ * (float)(255 - m)));
            }
            uint4 pk;
            pk.x = (unsigned)p[0] | ((unsigned)p[1] << 16);
            pk.y = (unsigned)p[2] | ((unsigned)p[3] << 16);
            pk.z = (unsigned)p[4] | ((unsigned)p[5] << 16);
            pk.w = (unsigned)p[6] | ((unsigned)p[7] << 16);
            *(uint4*)&dst[(size_t)d * 256 + half * 128 + mc] = pk;
        }
        __syncthreads();
    }
}

// ---------------------------------------------------------------------------
// S_0 = 0; write S_j^T (bf16); S_{j+1} = e^{-256 s} S_j + KV_j
// 512 WGs: (b,h) x 16 column-chunks; serial only over j.
// ---------------------------------------------------------------------------
__global__ __launch_bounds__(256) void scan_kv(const float* __restrict__ KVT,
                                               u16* __restrict__ ST,
                                               const float* __restrict__ slope) {
    const int bh = blockIdx.x >> 4, ch = blockIdx.x & 15;
    const int off = ch * 1024 + threadIdx.x * 4;
    const float bd = __expf(-256.f * slope[bh & 15]);
    float4 st = {0.f, 0.f, 0.f, 0.f};
    for (int j = 0; j < 16; j++) {
        const size_t base = ((size_t)(bh * 16 + j)) * 16384 + off;
        uint2 o;
        o.x = (unsigned)f2bf(st.x) | ((unsigned)f2bf(st.y) << 16);
        o.y = (unsigned)f2bf(st.z) | ((unsigned)f2bf(st.w) << 16);
        *(uint2*)&ST[base] = o;
        const float4 kv = *(const float4*)&KVT[base];
        st.x = bd * st.x + kv.x;
        st.y = bd * st.y + kv.y;
        st.z = bd * st.z + kv.z;
        st.w = bd * st.w + kv.w;
    }
}

// ---------------------------------------------------------------------------
// y = gate * (attn * rsqrt(mean(attn^2)+eps)) * norm_w   (one WG per row)
// ---------------------------------------------------------------------------
__global__ __launch_bounds__(256) void rmsnorm_gate(const u16* __restrict__ attn,
                                                    const u16* __restrict__ gate,
                                                    const float* __restrict__ nw,
                                                    u16* __restrict__ y) {
    const int r = blockIdx.x, tid = threadIdx.x;
    const size_t base = (size_t)r * HID + tid * 8;
    const uint4 a = *(const uint4*)&attn[base];
    float x[8];
    x[0] = bf2f(a.x & 0xffff); x[1] = bf2f(a.x >> 16);
    x[2] = bf2f(a.y & 0xffff); x[3] = bf2f(a.y >> 16);
    x[4] = bf2f(a.z & 0xffff); x[5] = bf2f(a.z >> 16);
    x[6] = bf2f(a.w & 0xffff); x[7] = bf2f(a.w >> 16);
    float s = 0.f;
    #pragma unroll
    for (int i = 0; i < 8; i++) s += x[i] * x[i];
    #pragma unroll
    for (int off = 32; off > 0; off >>= 1) s += __shfl_down(s, off);
    __shared__ float red[4];
    if ((tid & 63) == 0) red[tid >> 6] = s;
    __syncthreads();
    const float tot = red[0] + red[1] + red[2] + red[3];
    const float sc = rsqrtf(tot * (1.f / 2048.f) + 1e-6f);
    const uint4 g = *(const uint4*)&gate[base];
    float gv[8];
    gv[0] = bf2f(g.x & 0xffff); gv[1] = bf2f(g.x >> 16);
    gv[2] = bf2f(g.y & 0xffff); gv[3] = bf2f(g.y >> 16);
    gv[4] = bf2f(g.z & 0xffff); gv[5] = bf2f(g.z >> 16);
    gv[6] = bf2f(g.w & 0xffff); gv[7] = bf2f(g.w >> 16);
    const float4 w0 = *(const float4*)&nw[tid * 8];
    const float4 w1 = *(const float4*)&nw[tid * 8 + 4];
    const float wv[8] = {w0.x, w0.y, w0.z, w0.w, w1.x, w1.y, w1.z, w1.w};
    u16 o[8];
    #pragma unroll
    for (int i = 0; i < 8; i++) o[i] = f2bf(gv[i] * x[i] * sc * wv[i]);
    uint4 ov;
    ov.x = (unsigned)o[0] | ((unsigned)o[1] << 16);
    ov.y = (unsigned)o[2] | ((unsigned)o[3] << 16);
    ov.z = (unsigned)o[4] | ((unsigned)o[5] << 16);
    ov.w = (unsigned)o[6] | ((unsigned)o[7] << 16);
    *(uint4*)&y[base] = ov;
}

// ---------------------------------------------------------------------------
extern "C" void kernel_launch(void* const* d_in, const int* in_sizes, int n_in,
                              void* d_out, int out_size, void* d_ws, size_t ws_size,
                              hipStream_t stream) {
    const float* hidden = (const float*)d_in[0];
    const float* slope  = (const float*)d_in[1];
    const float* w_qkv  = (const float*)d_in[2];
    const float* w_gate = (const float*)d_in[3];
    const float* w_out  = (const float*)d_in[4];
    const float* norm_w = (const float*)d_in[5];
    float* out = (float*)d_out;

    // 7 slots x 33,554,432 B = 234,881,024 B total
    char* w = (char*)d_ws;
    u16* qb   = (u16*)(w);                 // S0: q                 [QKV .. intra#2]
    u16* kb   = (u16*)(w +  33554432);     // S1: k                 [QKV .. P#2]
    u16* kTs  = (u16*)(w +  67108864);     // S2: kTs               [transpose .. KVT]
    u16* hid_bf = (u16*)(w + 100663296);   // S3: hidden bf16       [cast .. QKV]
    u16* vT   = (u16*)(w + 134217728);     // S4: vT (via QKV)      [QKV .. intra#2]
    u16* gate = (u16*)(w + 167772160);     // S5: gate (via QKV)    [QKV .. rms]
    u16* wqkv_bf  = (u16*)(w + 201326592); // S6: w_qkv bf16 25.17M [cast .. QKV]
    u16* wgate_bf = (u16*)(w + 201326592 + 25165824); // S6 tail 8.39M, contiguous
    // aliases (disjoint lifetimes):
    float* KVT  = (float*)hid_bf;          // S3: KV^T fp32         [KVT .. scan]
    u16*   ST   = kTs;                     // S2: S^T bf16 16.8M    [scan .. intra#2]
    u16*   P    = hid_bf;                  // S3: P half            [P#1 .. intra#2]
    u16*   wout_bf = kb;                   // S1: w_out bf16        [cast .. OUT]
    u16*   attn = wqkv_bf;                 // S6: attn              [intra#1 .. rms]
    u16*   y    = kTs;                     // S2: y                 [rms .. OUT]

    static bool s_attr = false;
    if (!s_attr) {
        (void)hipFuncSetAttribute((const void*)gemm256<0>,
                                  hipFuncAttributeMaxDynamicSharedMemorySize, 65536);
        (void)hipFuncSetAttribute((const void*)gemm256<1>,
                                  hipFuncAttributeMaxDynamicSharedMemorySize, 65536);
        s_attr = true;
    }

    castk<<<16384, 256, 0, stream>>>(hidden, hid_bf);
    castk<<<12288, 256, 0, stream>>>(w_qkv,  wqkv_bf);
    castk<<< 4096, 256, 0, stream>>>(w_gate, wgate_bf);

    // fused qkv+gate: B = [w_qkv ; w_gate] (8192 x 2048 contiguous)
    gemm256<0><<<dim3(4096), dim3(256), 65536, stream>>>(hid_bf, wqkv_bf, qb, vT, gate);
    transpose_k     <<<512,             256, 0, stream>>>(kb, kTs, slope);
    gemm_nt<M_KVT ><<<dim3(1, 1, 512),  256, 0, stream>>>(vT, kTs, KVT, slope, 0, nullptr, nullptr);
    scan_kv         <<<512,             256, 0, stream>>>(KVT, ST, slope);
    gemm_nt<M_P   ><<<dim3(2, 2, 256),  256, 0, stream>>>(qb, kb, P, slope, 0, nullptr, nullptr);
    gemm_nt<M_INTRA><<<dim3(2, 1, 256), 256, 0, stream>>>(qb, ST, attn, slope, 0, P, vT);
    gemm_nt<M_P   ><<<dim3(2, 2, 256),  256, 0, stream>>>(qb, kb, P, slope, 256, nullptr, nullptr);
    gemm_nt<M_INTRA><<<dim3(2, 1, 256), 256, 0, stream>>>(qb, ST, attn, slope, 256, P, vT);
    castk<<< 4096, 256, 0, stream>>>(w_out, wout_bf);
    rmsnorm_gate    <<<8192,            256, 0, stream>>>(attn, gate, norm_w, y);
    gemm256<1><<<dim3(1024), dim3(256), 65536, stream>>>(y, wout_bf, (void*)out, nullptr, nullptr);
}

// Round 11
// 476.645 us; speedup vs baseline: 7.3649x; 1.0575x over previous
//
#include <hip/hip_runtime.h>

// ---------------------------------------------------------------------------
// MiniMax-M1 Lightning Attention forward, MI355X / gfx950.
//   0. cast fp32->bf16: hidden, w_qkv(+w_gate contiguous)
//   1. fused qkv+gate via 256x256 lockstep GEMM (R7 schedule) with ROTATED
//      ds_reads: each phase's frag reads are issued in the PREVIOUS phase's
//      post-MFMA section, so every lgkmcnt(0) drains reads queued a full
//      phase earlier (LDS drain hides under MFMA issue).
//   2. transpose_k: kTs[d][m] = silu_k[m][d] * exp(-s*(255-m))
//   3. KVT_j = vT @ kTs^T  (= KV_j^T, fp32)
//   4. scan: S_{j+1} = e^{-256 s} S_j + KV_j ; store S_j^T bf16  [512 WGs]
//   5. P = (q k^T) * diag_decay  per block   [2 half-launches, 1-slot P buffer]
//   6. intra+inter fused: acc = q @ S^T; acc *= q_decay(row); acc += P @ v
//   7. y = gate * rmsnorm(attn) * norm_w
//   8. out = y @ w_out^T via same 256 GEMM [fp32 -> d_out]
// Workspace: 7 slots x 33,554,432 B = 234,881,024 B peak (proven to fit).
// ---------------------------------------------------------------------------

typedef unsigned short u16;
typedef __bf16 bf16x8 __attribute__((ext_vector_type(8)));
typedef float f32x4 __attribute__((ext_vector_type(4)));

#define SEQ 4096
#define HID 2048

__device__ __forceinline__ u16 f2bf(float f) {
    union { float f; unsigned u; } v; v.f = f;
    unsigned r = v.u + 0x7fffu + ((v.u >> 16) & 1u);   // round-to-nearest-even
    return (u16)(r >> 16);
}
__device__ __forceinline__ float bf2f(u16 u) {
    union { unsigned u; float f; } v; v.u = ((unsigned)u) << 16; return v.f;
}

// async global->LDS, 16B per lane; lds dest must be wave-uniform base (+lane*16)
typedef __attribute__((address_space(1))) unsigned char gas_u8;
typedef __attribute__((address_space(3))) unsigned char las_u8;
__device__ __forceinline__ void gld16(const void* g, void* l) {
    __builtin_amdgcn_global_load_lds((gas_u8*)g, (las_u8*)l, 16, 0, 0);
}

// ---------------------------------------------------------------------------
// fp32 -> bf16 cast, 4 elems/thread, exact grids (n % 1024 == 0)
// ---------------------------------------------------------------------------
__global__ __launch_bounds__(256) void castk(const float* __restrict__ in,
                                             u16* __restrict__ out) {
    const size_t i = (size_t)blockIdx.x * 256 + threadIdx.x;
    const float4 f = *(const float4*)&in[i * 4];
    uint2 o;
    o.x = (unsigned)f2bf(f.x) | ((unsigned)f2bf(f.y) << 16);
    o.y = (unsigned)f2bf(f.z) | ((unsigned)f2bf(f.w) << 16);
    *(uint2*)&out[i * 4] = o;
}

// ---------------------------------------------------------------------------
// 256x256-tile lockstep pipelined NT GEMM (C = A[Mx2048] * B[Nx2048]^T).
// 512 threads = 8 waves (2M x 4N), each wave 128x64 out (8x4 16x16 frags).
// LDS 128 KiB: 2 K-tile buffers x (A 256x64 + B 256x64) bf16, XOR-swizzled
// via inverse-swizzled GLOBAL source (linear global_load_lds dest) + swizzled
// ds_read.  Counted vmcnt(6) at K-tile boundaries only; setprio(1) around
// each 16-MFMA quadrant.  R7 barrier structure (2 barriers/phase) with reads
// ROTATED one phase earlier (issued post-MFMA, drained by the NEXT phase's
// lgkmcnt(0)) so LDS drains overlap MFMA issue:
//   ph0: [STG A.hi(t+1)] bar lgkm0 MM(0,0)=A0*b0 ; read b1        bar
//   ph1: [STG B.lo(t+2)] bar lgkm0 MM(0,1)=A0*b1 ; read A1        bar
//   ph2: [STG B.hi(t+2)] bar lgkm0 MM(1,1)=A1*b1                  bar
//   ph3: [STG A.lo(t+2) vmcnt(6)] bar MM(1,0)=A1*b0 ; read A0',b0' bar
// WAR safety: b1 drains ph1-lgkm before STG B.lo lands; A1 drains ph2-lgkm
// before STG A.lo issues; A0'/b0' read buf t+1 (resident per ph3 vmcnt(6)+
// barrier) and drain at next ph0-lgkm before any overwrite of that buffer.
// MODE 0: fused QKV+gate epilogue; MODE 1: f32 out.
// ---------------------------------------------------------------------------
template <int MODE>
__global__ __launch_bounds__(512, 2) void gemm256(const u16* __restrict__ A,
                                                  const u16* __restrict__ Bm,
                                                  void* __restrict__ Cv,
                                                  void* __restrict__ aux,
                                                  void* __restrict__ aux2) {
    constexpr int NTN = (MODE == 0) ? 32 : 8;     // tiles along N
    constexpr int NT  = 32;                       // K tiles (2048 / 64)
    extern __shared__ u16 smem[];                 // [2][A 16384 | B 16384]

    // XCD swizzle: 8 XCDs; per-XCD 4-row x 8-col rectangular supertiles
    const int bid = blockIdx.x;
    const int xcd = bid & 7, l = bid >> 3;
    int tm, tn;
    if constexpr (MODE == 0) {       // 32x32 tile grid, 128 WGs per XCD
        tm = xcd * 4 + (l & 3);
        tn = ((l >> 2) & 7) | ((l >> 5) << 3);
    } else {                         // 32x8 grid, 32 WGs per XCD (4x8 rect)
        const int wgid = xcd * 32 + l;
        tm = wgid / NTN; tn = wgid % NTN;
    }

    const int tid  = threadIdx.x;
    const int lane = tid & 63, wv = tid >> 6;
    const int quad = lane >> 4, cl = lane & 15;
    const int wm = (wv & 1) * 128, wn = (wv >> 1) * 64;

    // staging: thread t covers row srw (0..63 per issue), 16B chunk (t&7),
    // global chunk pre-XORed so linear LDS dest holds the swizzled layout
    const int srw  = tid >> 3;
    const int colo = ((tid & 7) ^ (srw & 7)) * 8;
    const u16* gA0 = A  + (size_t)(tm * 256 + srw) * HID + colo;
    const u16* gB0 = Bm + (size_t)(tn * 256 + srw) * HID + colo;

    // ds_read swizzle: LDS (row, slot) holds global chunk slot^(row&7); frag
    // row base is 16-aligned so row&7 == cl&7
    const int x0 = ((quad       ^ (cl & 7)) * 8);
    const int x1 = (((4 + quad) ^ (cl & 7)) * 8);

    f32x4 acc[8][4];
    const f32x4 zero = {0.f, 0.f, 0.f, 0.f};
    #pragma unroll
    for (int a = 0; a < 8; a++)
        #pragma unroll
        for (int b = 0; b < 4; b++) acc[a][b] = zero;

    bf16x8 af[8], b0[4], b1[4];

    auto STG = [&](int kt, int mat, int hh) {   // stage one 128x64 half-tile
        const u16* g = (mat ? gB0 : gA0) + (size_t)(hh * 128) * HID + kt * 64;
        u16* lp = smem + (kt & 1) * 32768 + mat * 16384 + hh * 8192 + wv * 512;
        gld16(g, lp);
        gld16(g + (size_t)64 * HID, lp + 4096);
    };
    auto LDA = [&](int qm, int ab) {
        #pragma unroll
        for (int mi = 0; mi < 4; mi++) {
            const int rr = (wm + qm * 64 + mi * 16 + cl) * 64 + ab;
            af[mi * 2 + 0] = *(const bf16x8*)&smem[rr + x0];
            af[mi * 2 + 1] = *(const bf16x8*)&smem[rr + x1];
        }
    };
    auto LDB = [&](bf16x8* d, int qn, int bb2) {
        #pragma unroll
        for (int ni = 0; ni < 2; ni++) {
            const int rr = (wn + qn * 32 + ni * 16 + cl) * 64 + bb2;
            d[ni * 2 + 0] = *(const bf16x8*)&smem[rr + x0];
            d[ni * 2 + 1] = *(const bf16x8*)&smem[rr + x1];
        }
    };
    auto MM = [&](int qm, int qn, const bf16x8* bv) {
        #pragma unroll
        for (int mi = 0; mi < 4; mi++)
            #pragma unroll
            for (int ni = 0; ni < 2; ni++) {
                f32x4 c = acc[qm * 4 + mi][qn * 2 + ni];
                c = __builtin_amdgcn_mfma_f32_16x16x32_bf16(af[mi * 2 + 0], bv[ni * 2 + 0], c, 0, 0, 0);
                c = __builtin_amdgcn_mfma_f32_16x16x32_bf16(af[mi * 2 + 1], bv[ni * 2 + 1], c, 0, 0, 0);
                acc[qm * 4 + mi][qn * 2 + ni] = c;
            }
    };

    // prologue: issue stream per tile = B.lo, B.hi, A.lo, A.hi
    STG(0, 1, 0); STG(0, 1, 1); STG(0, 0, 0); STG(0, 0, 1);
    STG(1, 1, 0); STG(1, 1, 1); STG(1, 0, 0);
    asm volatile("s_waitcnt vmcnt(6)" ::: "memory");   // tile 0 resident
    __builtin_amdgcn_s_barrier();
    LDA(0, 0); LDB(b0, 0, 16384);      // ph0 operands (drain at ph0 lgkm(0))

    #pragma unroll 2
    for (int t = 0; t < NT; ++t) {
        const int ab  = (t & 1) * 32768;
        const int bb2 = ab + 16384;
        const int nab = ((t + 1) & 1) * 32768;
        // phase 0: MM(0,0)=A0*b0 (reads from prev ph3/prologue); read b1
        if (t + 1 < NT) STG(t + 1, 0, 1);
        __builtin_amdgcn_s_barrier();
        asm volatile("s_waitcnt lgkmcnt(0)" ::: "memory");
        __builtin_amdgcn_s_setprio(1); MM(0, 0, b0); __builtin_amdgcn_s_setprio(0);
        LDB(b1, 1, bb2);
        __builtin_amdgcn_s_barrier();
        // phase 1: MM(0,1)=A0*b1; read A1
        if (t + 2 < NT) STG(t + 2, 1, 0);
        __builtin_amdgcn_s_barrier();
        asm volatile("s_waitcnt lgkmcnt(0)" ::: "memory");
        __builtin_amdgcn_s_setprio(1); MM(0, 1, b1); __builtin_amdgcn_s_setprio(0);
        LDA(1, ab);
        __builtin_amdgcn_s_barrier();
        // phase 2: MM(1,1)=A1*b1
        if (t + 2 < NT) STG(t + 2, 1, 1);
        __builtin_amdgcn_s_barrier();
        asm volatile("s_waitcnt lgkmcnt(0)" ::: "memory");
        __builtin_amdgcn_s_setprio(1); MM(1, 1, b1); __builtin_amdgcn_s_setprio(0);
        __builtin_amdgcn_s_barrier();
        // phase 3: MM(1,0)=A1*b0; boundary vmcnt(6) -> tile t+1 resident;
        // post-MFMA: read next tile's A0,b0 from the other buffer
        if (t + 2 < NT) {
            STG(t + 2, 0, 0);
            asm volatile("s_waitcnt vmcnt(6)" ::: "memory");
        } else {
            asm volatile("s_waitcnt vmcnt(0)" ::: "memory");
        }
        __builtin_amdgcn_s_barrier();
        __builtin_amdgcn_s_setprio(1); MM(1, 0, b0); __builtin_amdgcn_s_setprio(0);
        if (t + 1 < NT) { LDA(0, nab); LDB(b0, 0, nab + 16384); }
        __builtin_amdgcn_s_barrier();
    }

    // epilogue: m = tm*256 + wm + (a>>2)*64 + (a&3)*16 + quad*4 + r
    //           n = tn*256 + wn + (b>>1)*32 + (b&1)*16 + cl
    if constexpr (MODE == 0) {
        // 128-col group is wave-uniform: grp 0-15 q | 16-31 k | 32-47 v | 48-63 gate
        const int grp = tn * 2 + (wn >> 7);
        const int which = grp >> 4, hd = grp & 15;
        const int n64 = wn & 64;
        if (which == 2) {
            // vT[bz][d][m]: lane holds 4 consecutive m at fixed d -> uint2
            const size_t bz = (size_t)((tm >> 4) * 256 + hd * 16 + (tm & 15));
            u16* tdst = (u16*)aux + bz * 32768;
            #pragma unroll
            for (int a = 0; a < 8; a++) {
                const int mm = wm + (a >> 2) * 64 + (a & 3) * 16 + quad * 4;
                #pragma unroll
                for (int b = 0; b < 4; b++) {
                    const int d = n64 + (b >> 1) * 32 + (b & 1) * 16 + cl;
                    u16 p[4];
                    #pragma unroll
                    for (int r = 0; r < 4; r++) {
                        const float x = acc[a][b][r];
                        p[r] = f2bf(x / (1.f + __expf(-x)));
                    }
                    uint2 pk;
                    pk.x = (unsigned)p[0] | ((unsigned)p[1] << 16);
                    pk.y = (unsigned)p[2] | ((unsigned)p[3] << 16);
                    *(uint2*)&tdst[(size_t)d * 256 + mm] = pk;
                }
            }
            return;
        }
        u16* dst = (which == 0) ? (u16*)Cv
                 : (which == 1) ? (u16*)Cv + (size_t)16777216   // k slot (S1)
                                : (u16*)aux2;                   // gate slot
        #pragma unroll
        for (int a = 0; a < 8; a++)
            #pragma unroll
            for (int b = 0; b < 4; b++)
                #pragma unroll
                for (int r = 0; r < 4; r++) {
                    const int m = tm * 256 + wm + (a >> 2) * 64 + (a & 3) * 16 + quad * 4 + r;
                    const int col = hd * 128 + n64 + (b >> 1) * 32 + (b & 1) * 16 + cl;
                    const float x = acc[a][b][r];
                    const float v = (which == 3) ? 1.f / (1.f + __expf(-x))
                                                 : x / (1.f + __expf(-x));
                    dst[(size_t)m * HID + col] = f2bf(v);
                }
        return;
    } else {
        float* C = (float*)Cv;
        #pragma unroll
        for (int a = 0; a < 8; a++)
            #pragma unroll
            for (int b = 0; b < 4; b++)
                #pragma unroll
                for (int r = 0; r < 4; r++) {
                    const int m = tm * 256 + wm + (a >> 2) * 64 + (a & 3) * 16 + quad * 4 + r;
                    const int n = tn * 256 + wn + (b >> 1) * 32 + (b & 1) * 16 + cl;
                    C[(size_t)m * HID + n] = acc[a][b][r];
                }
    }
}

// ---------------------------------------------------------------------------
// Generic 128x128-tile NT GEMM for the small per-(b,h,block) ops.
// ---------------------------------------------------------------------------
#define M_QKV   0
#define M_P     2
#define M_INTRA 3
#define M_KVT   4
#define M_OUT   6

template <int MODE>
__global__ __launch_bounds__(256) void gemm_nt(const u16* __restrict__ A,
                                               const u16* __restrict__ Bm,
                                               void* __restrict__ Cv,
                                               const float* __restrict__ slope,
                                               int bz0,
                                               void* __restrict__ aux,
                                               void* __restrict__ aux2) {
    constexpr int NPH = (MODE == M_INTRA) ? 2 : 1;
    const int tid = threadIdx.x;
    const int tm = blockIdx.x, tn = blockIdx.y;
    const int bzl = blockIdx.z;           // local z (P buffer index)
    const int bz  = bzl + bz0;            // global (b,h,block) index

    int bb = 0, hh = 0, jb = 0;
    if constexpr (MODE == M_P || MODE == M_INTRA || MODE == M_KVT) {
        bb = bz >> 8; hh = (bz >> 4) & 15; jb = bz & 15;
    }

    if constexpr (MODE == M_P) {
        // tile fully above the (block-local) diagonal -> all zeros, skip GEMM
        if (tn > tm) {
            u16* C = (u16*)Cv + (size_t)bzl * 65536 + tm * 128 * 256 + tn * 128;
            uint4 z = make_uint4(0u, 0u, 0u, 0u);
            #pragma unroll
            for (int i = 0; i < 8; i++) {
                int f = tid + 256 * i;
                int row = f >> 4, c8 = (f & 15) * 8;
                *(uint4*)&C[row * 256 + c8] = z;
            }
            return;
        }
    }

    __shared__ u16 smem[8192];            // As/Bs staging, 16,384 B
    u16 (*As)[32] = (u16(*)[32])smem;
    u16 (*Bs)[32] = (u16(*)[32])(smem + 4096);

    const int lane = tid & 63, wv = tid >> 6;
    const int wm = (wv & 1) * 64, wn = (wv >> 1) * 64;
    const int quad = lane >> 4, cl = lane & 15;
    const int lr = lane >> 2;            // 0..15: row within 16-row chunk
    const int lc = (lane & 3) * 8;       // 0/8/16/24: col elem offset
    u16* lA = &As[wv * 32][0];           // wave-uniform LDS bases
    u16* lB = &Bs[wv * 32][0];

    f32x4 acc[4][4];
    const f32x4 zero = {0.f, 0.f, 0.f, 0.f};
    #pragma unroll
    for (int mi = 0; mi < 4; mi++)
        #pragma unroll
        for (int ni = 0; ni < 4; ni++) acc[mi][ni] = zero;

    #pragma unroll
    for (int ph = 0; ph < NPH; ph++) {
        const u16* Ab; const u16* Bb; int lda, ldb, kmax;
        if constexpr (MODE == M_QKV || MODE == M_OUT) {
            Ab = A; lda = HID; Bb = Bm; ldb = HID; kmax = 2048;
        } else if constexpr (MODE == M_P) {
            const size_t o = ((size_t)(bb * SEQ + jb * 256)) * HID + hh * 128;
            Ab = A + o; lda = HID;                     // q rows
            Bb = Bm + o; ldb = HID;                    // k rows
            kmax = 128;
        } else if constexpr (MODE == M_KVT) {
            Ab = A + (size_t)bz * 32768; lda = 256;    // vT
            Bb = Bm + (size_t)bz * 32768; ldb = 256;   // kTs
            kmax = 256;
        } else { // M_INTRA
            if (ph == 0) {  // inter: q @ S^T
                Ab = A + ((size_t)(bb * SEQ + jb * 256)) * HID + hh * 128; lda = HID;
                Bb = Bm + (size_t)bz * 16384; ldb = 128;   // S^T bf16
                kmax = 128;
            } else {        // intra: P @ v
                Ab = (const u16*)aux + (size_t)bzl * 65536; lda = 256;   // P
                Bb = (const u16*)aux2 + (size_t)bz * 32768; ldb = 256;   // vT
                kmax = (tm == 0) ? 128 : 256;          // P upper half is 0
            }
        }
        const u16* gA = Ab + (size_t)(tm * 128 + wv * 32 + lr) * lda + lc;
        const u16* gB = Bb + (size_t)(tn * 128 + wv * 32 + lr) * ldb + lc;

        for (int k0 = 0; k0 < kmax; k0 += 32) {
            __syncthreads();
            gld16(gA + k0,                    lA);
            gld16(gA + k0 + (size_t)16 * lda, lA + 16 * 32);
            gld16(gB + k0,                    lB);
            gld16(gB + k0 + (size_t)16 * ldb, lB + 16 * 32);
            __syncthreads();
            const int ko = quad * 8;
            bf16x8 af[4], bfv[4];
            #pragma unroll
            for (int mi = 0; mi < 4; mi++) af[mi] = *(const bf16x8*)&As[wm + mi * 16 + cl][ko];
            #pragma unroll
            for (int ni = 0; ni < 4; ni++) bfv[ni] = *(const bf16x8*)&Bs[wn + ni * 16 + cl][ko];
            #pragma unroll
            for (int mi = 0; mi < 4; mi++)
                #pragma unroll
                for (int ni = 0; ni < 4; ni++)
                    acc[mi][ni] = __builtin_amdgcn_mfma_f32_16x16x32_bf16(af[mi], bfv[ni], acc[mi][ni], 0, 0, 0);
        }

        if constexpr (MODE == M_INTRA) {
            if (ph == 0) {   // scale inter part by q_decay(row)
                const float s_ = slope[hh];
                #pragma unroll
                for (int mi = 0; mi < 4; mi++)
                    #pragma unroll
                    for (int r = 0; r < 4; r++) {
                        const int m = tm * 128 + wm + mi * 16 + quad * 4 + r;
                        const float qd = __expf(-s_ * (float)(m + 1));
                        #pragma unroll
                        for (int ni = 0; ni < 4; ni++) acc[mi][ni][r] *= qd;
                    }
            }
        }
    }

    float sl = 0.f;
    if constexpr (MODE == M_P) sl = slope[hh];

    #pragma unroll
    for (int mi = 0; mi < 4; mi++) {
        #pragma unroll
        for (int ni = 0; ni < 4; ni++) {
            const f32x4 v = acc[mi][ni];
            #pragma unroll
            for (int r = 0; r < 4; r++) {
                const int m = tm * 128 + wm + mi * 16 + quad * 4 + r;  // C row (A index)
                const int n = tn * 128 + wn + ni * 16 + cl;            // C col (B index)
                const float x = v[r];
                if constexpr (MODE == M_P) {
                    const int d = m - n;
                    ((u16*)Cv)[(size_t)bzl * 65536 + m * 256 + n] =
                        f2bf(d >= 0 ? x * __expf(-sl * (float)d) : 0.f);
                } else if constexpr (MODE == M_INTRA) {
                    ((u16*)Cv)[((size_t)(bb * SEQ + jb * 256 + m)) * HID + hh * 128 + n] = f2bf(x);
                } else if constexpr (MODE == M_KVT) {
                    ((float*)Cv)[(size_t)bz * 16384 + m * 128 + n] = x;
                } else { // M_OUT
                    ((float*)Cv)[(size_t)m * HID + n] = x;
                }
            }
        }
    }
}

// ---------------------------------------------------------------------------
// Per (b,h,block): kTs[d][m] = k[m][d] * exp(-s*(255-m))  (vectorized stores)
// ---------------------------------------------------------------------------
__global__ __launch_bounds__(256) void transpose_k(const u16* __restrict__ kb,
                                                   u16* __restrict__ kTs,
                                                   const float* __restrict__ slope) {
    __shared__ u16 t[128][137];   // pad 137: transposed-read lanes land 2-way max
    const int bz = blockIdx.x;
    const int bb = bz >> 8, hh = (bz >> 4) & 15, jb = bz & 15;
    const int tid = threadIdx.x;
    const float s_ = slope[hh];
    const u16* src = kb + ((size_t)(bb * SEQ + jb * 256)) * HID + hh * 128;
    u16* dst = kTs + (size_t)bz * 32768;

    for (int half = 0; half < 2; half++) {
        #pragma unroll
        for (int i = 0; i < 8; i++) {
            const int flat = tid + 256 * i;
            const int row = flat >> 4, c8 = (flat & 15) * 8;
            *(uint4*)&t[row][c8] = *(const uint4*)&src[(size_t)(half * 128 + row) * HID + c8];
        }
        __syncthreads();
        #pragma unroll
        for (int i = 0; i < 8; i++) {
            const int flat = tid + 256 * i;
            const int d = flat >> 4, mc = (flat & 15) * 8;
            u16 p[8];
            #pragma unroll
            for (int j = 0; j < 8; j++) {
                const int m = half * 128 + mc + j;
                p[j] = f2bf(bf2f(t[mc + j][d]) * __expf(-s_ * (float)(255 - m)));
            }
            uint4 pk;
            pk.x = (unsigned)p[0] | ((unsigned)p[1] << 16);
            pk.y = (unsigned)p[2] | ((unsigned)p[3] << 16);
            pk.z = (unsigned)p[4] | ((unsigned)p[5] << 16);
            pk.w = (unsigned)p[6] | ((unsigned)p[7] << 16);
            *(uint4*)&dst[(size_t)d * 256 + half * 128 + mc] = pk;
        }
        __syncthreads();
    }
}

// ---------------------------------------------------------------------------
// S_0 = 0; write S_j^T (bf16); S_{j+1} = e^{-256 s} S_j + KV_j
// 512 WGs: (b,h) x 16 column-chunks; serial only over j.
// ---------------------------------------------------------------------------
__global__ __launch_bounds__(256) void scan_kv(const float* __restrict__ KVT,
                                               u16* __restrict__ ST,
                                               const float* __restrict__ slope) {
    const int bh = blockIdx.x >> 4, ch = blockIdx.x & 15;
    const int off = ch * 1024 + threadIdx.x * 4;
    const float bd = __expf(-256.f * slope[bh & 15]);
    float4 st = {0.f, 0.f, 0.f, 0.f};
    for (int j = 0; j < 16; j++) {
        const size_t base = ((size_t)(bh * 16 + j)) * 16384 + off;
        uint2 o;
        o.x = (unsigned)f2bf(st.x) | ((unsigned)f2bf(st.y) << 16);
        o.y = (unsigned)f2bf(st.z) | ((unsigned)f2bf(st.w) << 16);
        *(uint2*)&ST[base] = o;
        const float4 kv = *(const float4*)&KVT[base];
        st.x = bd * st.x + kv.x;
        st.y = bd * st.y + kv.y;
        st.z = bd * st.z + kv.z;
        st.w = bd * st.w + kv.w;
    }
}

// ---------------------------------------------------------------------------
// y = gate * (attn * rsqrt(mean(attn^2)+eps)) * norm_w   (one WG per row)
// ---------------------------------------------------------------------------
__global__ __launch_bounds__(256) void rmsnorm_gate(const u16* __restrict__ attn,
                                                    const u16* __restrict__ gate,
                                                    const float* __restrict__ nw,
                                                    u16* __restrict__ y) {
    const int r = blockIdx.x, tid = threadIdx.x;
    const size_t base = (size_t)r * HID + tid * 8;
    const uint4 a = *(const uint4*)&attn[base];
    float x[8];
    x[0] = bf2f(a.x & 0xffff); x[1] = bf2f(a.x >> 16);
    x[2] = bf2f(a.y & 0xffff); x[3] = bf2f(a.y >> 16);
    x[4] = bf2f(a.z & 0xffff); x[5] = bf2f(a.z >> 16);
    x[6] = bf2f(a.w & 0xffff); x[7] = bf2f(a.w >> 16);
    float s = 0.f;
    #pragma unroll
    for (int i = 0; i < 8; i++) s += x[i] * x[i];
    #pragma unroll
    for (int off = 32; off > 0; off >>= 1) s += __shfl_down(s, off);
    __shared__ float red[4];
    if ((tid & 63) == 0) red[tid >> 6] = s;
    __syncthreads();
    const float tot = red[0] + red[1] + red[2] + red[3];
    const float sc = rsqrtf(tot * (1.f / 2048.f) + 1e-6f);
    const uint4 g = *(const uint4*)&gate[base];
    float gv[8];
    gv[0] = bf2f(g.x & 0xffff); gv[1] = bf2f(g.x >> 16);
    gv[2] = bf2f(g.y & 0xffff); gv[3] = bf2f(g.y >> 16);
    gv[4] = bf2f(g.z & 0xffff); gv[5] = bf2f(g.z >> 16);
    gv[6] = bf2f(g.w & 0xffff); gv[7] = bf2f(g.w >> 16);
    const float4 w0 = *(const float4*)&nw[tid * 8];
    const float4 w1 = *(const float4*)&nw[tid * 8 + 4];
    const float wv[8] = {w0.x, w0.y, w0.z, w0.w, w1.x, w1.y, w1.z, w1.w};
    u16 o[8];
    #pragma unroll
    for (int i = 0; i < 8; i++) o[i] = f2bf(gv[i] * x[i] * sc * wv[i]);
    uint4 ov;
    ov.x = (unsigned)o[0] | ((unsigned)o[1] << 16);
    ov.y = (unsigned)o[2] | ((unsigned)o[3] << 16);
    ov.z = (unsigned)o[4] | ((unsigned)o[5] << 16);
    ov.w = (unsigned)o[6] | ((unsigned)o[7] << 16);
    *(uint4*)&y[base] = ov;
}

// ---------------------------------------------------------------------------
extern "C" void kernel_launch(void* const* d_in, const int* in_sizes, int n_in,
                              void* d_out, int out_size, void* d_ws, size_t ws_size,
                              hipStream_t stream) {
    const float* hidden = (const float*)d_in[0];
    const float* slope  = (const float*)d_in[1];
    const float* w_qkv  = (const float*)d_in[2];
    const float* w_gate = (const float*)d_in[3];
    const float* w_out  = (const float*)d_in[4];
    const float* norm_w = (const float*)d_in[5];
    float* out = (float*)d_out;

    // 7 slots x 33,554,432 B = 234,881,024 B total
    char* w = (char*)d_ws;
    u16* qb   = (u16*)(w);                 // S0: q                 [QKV .. intra#2]
    u16* kb   = (u16*)(w +  33554432);     // S1: k                 [QKV .. P#2]
    u16* kTs  = (u16*)(w +  67108864);     // S2: kTs               [transpose .. KVT]
    u16* hid_bf = (u16*)(w + 100663296);   // S3: hidden bf16       [cast .. QKV]
    u16* vT   = (u16*)(w + 134217728);     // S4: vT (via QKV)      [QKV .. intra#2]
    u16* gate = (u16*)(w + 167772160);     // S5: gate (via QKV)    [QKV .. rms]
    u16* wqkv_bf  = (u16*)(w + 201326592); // S6: w_qkv bf16 25.17M [cast .. QKV]
    u16* wgate_bf = (u16*)(w + 201326592 + 25165824); // S6 tail 8.39M, contiguous
    // aliases (disjoint lifetimes):
    float* KVT  = (float*)hid_bf;          // S3: KV^T fp32         [KVT .. scan]
    u16*   ST   = kTs;                     // S2: S^T bf16 16.8M    [scan .. intra#2]
    u16*   P    = hid_bf;                  // S3: P half            [P#1 .. intra#2]
    u16*   wout_bf = kb;                   // S1: w_out bf16        [cast .. OUT]
    u16*   attn = wqkv_bf;                 // S6: attn              [intra#1 .. rms]
    u16*   y    = kTs;                     // S2: y                 [rms .. OUT]

    static bool s_attr = false;
    if (!s_attr) {
        (void)hipFuncSetAttribute((const void*)gemm256<0>,
                                  hipFuncAttributeMaxDynamicSharedMemorySize, 131072);
        (void)hipFuncSetAttribute((const void*)gemm256<1>,
                                  hipFuncAttributeMaxDynamicSharedMemorySize, 131072);
        s_attr = true;
    }

    castk<<<16384, 256, 0, stream>>>(hidden, hid_bf);
    castk<<<12288, 256, 0, stream>>>(w_qkv,  wqkv_bf);
    castk<<< 4096, 256, 0, stream>>>(w_gate, wgate_bf);

    // fused qkv+gate: B = [w_qkv ; w_gate] (8192 x 2048 contiguous)
    gemm256<0><<<dim3(1024), dim3(512), 131072, stream>>>(hid_bf, wqkv_bf, qb, vT, gate);
    transpose_k     <<<512,             256, 0, stream>>>(kb, kTs, slope);
    gemm_nt<M_KVT ><<<dim3(1, 1, 512),  256, 0, stream>>>(vT, kTs, KVT, slope, 0, nullptr, nullptr);
    scan_kv         <<<512,             256, 0, stream>>>(KVT, ST, slope);
    gemm_nt<M_P   ><<<dim3(2, 2, 256),  256, 0, stream>>>(qb, kb, P, slope, 0, nullptr, nullptr);
    gemm_nt<M_INTRA><<<dim3(2, 1, 256), 256, 0, stream>>>(qb, ST, attn, slope, 0, P, vT);
    gemm_nt<M_P   ><<<dim3(2, 2, 256),  256, 0, stream>>>(qb, kb, P, slope, 256, nullptr, nullptr);
    gemm_nt<M_INTRA><<<dim3(2, 1, 256), 256, 0, stream>>>(qb, ST, attn, slope, 256, P, vT);
    castk<<< 4096, 256, 0, stream>>>(w_out, wout_bf);
    rmsnorm_gate    <<<8192,            256, 0, stream>>>(attn, gate, norm_w, y);
    gemm256<1><<<dim3(256), dim3(512), 131072, stream>>>(y, wout_bf, (void*)out, nullptr, nullptr);
}

// Round 12
// 447.889 us; speedup vs baseline: 7.8377x; 1.0642x over previous
//
#include <hip/hip_runtime.h>

// ---------------------------------------------------------------------------
// MiniMax-M1 Lightning Attention forward, MI355X / gfx950.
//   0. cast fp32->bf16: hidden, w_qkv(+w_gate contiguous)
//   1. fused qkv+gate via 256x256 lockstep GEMM (R11 rotated-read schedule)
//   2. transpose_k: kTs[d][m] = silu_k[m][d] * exp(-s*(255-m))
//   3. KVT_j = vT @ kTs^T  (= KV_j^T, fp32)
//   4. scan: S_{j+1} = e^{-256 s} S_j + KV_j ; store S_j^T bf16  [512 WGs]
//   5+6 FUSED (fused_pv): per (b,h,block,row-half):
//      acc = q @ S^T (q_decay-scaled);  then per 32-kv chunk: P-chunk =
//      (q k^T)*diag_decay computed in-register -> LDS round-trip -> acc += P@v
//      (no global P buffer, no zero-tile writes, 1 launch instead of 4)
//   7. y = gate * rmsnorm(attn) * norm_w
//   8. out = y @ w_out^T via same 256 GEMM [fp32 -> d_out]
// Workspace: 7 slots x 33,554,432 B = 234,881,024 B peak (P slot now unused).
// ---------------------------------------------------------------------------

typedef unsigned short u16;
typedef __bf16 bf16x8 __attribute__((ext_vector_type(8)));
typedef float f32x4 __attribute__((ext_vector_type(4)));

#define SEQ 4096
#define HID 2048

__device__ __forceinline__ u16 f2bf(float f) {
    union { float f; unsigned u; } v; v.f = f;
    unsigned r = v.u + 0x7fffu + ((v.u >> 16) & 1u);   // round-to-nearest-even
    return (u16)(r >> 16);
}
__device__ __forceinline__ float bf2f(u16 u) {
    union { unsigned u; float f; } v; v.u = ((unsigned)u) << 16; return v.f;
}

// async global->LDS, 16B per lane; lds dest must be wave-uniform base (+lane*16)
typedef __attribute__((address_space(1))) unsigned char gas_u8;
typedef __attribute__((address_space(3))) unsigned char las_u8;
__device__ __forceinline__ void gld16(const void* g, void* l) {
    __builtin_amdgcn_global_load_lds((gas_u8*)g, (las_u8*)l, 16, 0, 0);
}

// ---------------------------------------------------------------------------
// fp32 -> bf16 cast, 4 elems/thread, exact grids (n % 1024 == 0)
// ---------------------------------------------------------------------------
__global__ __launch_bounds__(256) void castk(const float* __restrict__ in,
                                             u16* __restrict__ out) {
    const size_t i = (size_t)blockIdx.x * 256 + threadIdx.x;
    const float4 f = *(const float4*)&in[i * 4];
    uint2 o;
    o.x = (unsigned)f2bf(f.x) | ((unsigned)f2bf(f.y) << 16);
    o.y = (unsigned)f2bf(f.z) | ((unsigned)f2bf(f.w) << 16);
    *(uint2*)&out[i * 4] = o;
}

// ---------------------------------------------------------------------------
// 256x256-tile lockstep pipelined NT GEMM (R11 rotated-read schedule).
// MODE 0: fused QKV+gate epilogue; MODE 1: f32 out.
// ---------------------------------------------------------------------------
template <int MODE>
__global__ __launch_bounds__(512, 2) void gemm256(const u16* __restrict__ A,
                                                  const u16* __restrict__ Bm,
                                                  void* __restrict__ Cv,
                                                  void* __restrict__ aux,
                                                  void* __restrict__ aux2) {
    constexpr int NTN = (MODE == 0) ? 32 : 8;     // tiles along N
    constexpr int NT  = 32;                       // K tiles (2048 / 64)
    extern __shared__ u16 smem[];                 // [2][A 16384 | B 16384]

    // XCD swizzle: 8 XCDs; per-XCD 4-row x 8-col rectangular supertiles
    const int bid = blockIdx.x;
    const int xcd = bid & 7, l = bid >> 3;
    int tm, tn;
    if constexpr (MODE == 0) {       // 32x32 tile grid, 128 WGs per XCD
        tm = xcd * 4 + (l & 3);
        tn = ((l >> 2) & 7) | ((l >> 5) << 3);
    } else {                         // 32x8 grid, 32 WGs per XCD (4x8 rect)
        const int wgid = xcd * 32 + l;
        tm = wgid / NTN; tn = wgid % NTN;
    }

    const int tid  = threadIdx.x;
    const int lane = tid & 63, wv = tid >> 6;
    const int quad = lane >> 4, cl = lane & 15;
    const int wm = (wv & 1) * 128, wn = (wv >> 1) * 64;

    const int srw  = tid >> 3;
    const int colo = ((tid & 7) ^ (srw & 7)) * 8;
    const u16* gA0 = A  + (size_t)(tm * 256 + srw) * HID + colo;
    const u16* gB0 = Bm + (size_t)(tn * 256 + srw) * HID + colo;

    const int x0 = ((quad       ^ (cl & 7)) * 8);
    const int x1 = (((4 + quad) ^ (cl & 7)) * 8);

    f32x4 acc[8][4];
    const f32x4 zero = {0.f, 0.f, 0.f, 0.f};
    #pragma unroll
    for (int a = 0; a < 8; a++)
        #pragma unroll
        for (int b = 0; b < 4; b++) acc[a][b] = zero;

    bf16x8 af[8], b0[4], b1[4];

    auto STG = [&](int kt, int mat, int hh) {   // stage one 128x64 half-tile
        const u16* g = (mat ? gB0 : gA0) + (size_t)(hh * 128) * HID + kt * 64;
        u16* lp = smem + (kt & 1) * 32768 + mat * 16384 + hh * 8192 + wv * 512;
        gld16(g, lp);
        gld16(g + (size_t)64 * HID, lp + 4096);
    };
    auto LDA = [&](int qm, int ab) {
        #pragma unroll
        for (int mi = 0; mi < 4; mi++) {
            const int rr = (wm + qm * 64 + mi * 16 + cl) * 64 + ab;
            af[mi * 2 + 0] = *(const bf16x8*)&smem[rr + x0];
            af[mi * 2 + 1] = *(const bf16x8*)&smem[rr + x1];
        }
    };
    auto LDB = [&](bf16x8* d, int qn, int bb2) {
        #pragma unroll
        for (int ni = 0; ni < 2; ni++) {
            const int rr = (wn + qn * 32 + ni * 16 + cl) * 64 + bb2;
            d[ni * 2 + 0] = *(const bf16x8*)&smem[rr + x0];
            d[ni * 2 + 1] = *(const bf16x8*)&smem[rr + x1];
        }
    };
    auto MM = [&](int qm, int qn, const bf16x8* bv) {
        #pragma unroll
        for (int mi = 0; mi < 4; mi++)
            #pragma unroll
            for (int ni = 0; ni < 2; ni++) {
                f32x4 c = acc[qm * 4 + mi][qn * 2 + ni];
                c = __builtin_amdgcn_mfma_f32_16x16x32_bf16(af[mi * 2 + 0], bv[ni * 2 + 0], c, 0, 0, 0);
                c = __builtin_amdgcn_mfma_f32_16x16x32_bf16(af[mi * 2 + 1], bv[ni * 2 + 1], c, 0, 0, 0);
                acc[qm * 4 + mi][qn * 2 + ni] = c;
            }
    };

    // prologue: issue stream per tile = B.lo, B.hi, A.lo, A.hi
    STG(0, 1, 0); STG(0, 1, 1); STG(0, 0, 0); STG(0, 0, 1);
    STG(1, 1, 0); STG(1, 1, 1); STG(1, 0, 0);
    asm volatile("s_waitcnt vmcnt(6)" ::: "memory");   // tile 0 resident
    __builtin_amdgcn_s_barrier();
    LDA(0, 0); LDB(b0, 0, 16384);      // ph0 operands (drain at ph0 lgkm(0))

    #pragma unroll 2
    for (int t = 0; t < NT; ++t) {
        const int ab  = (t & 1) * 32768;
        const int bb2 = ab + 16384;
        const int nab = ((t + 1) & 1) * 32768;
        // phase 0: MM(0,0)=A0*b0 (reads from prev ph3/prologue); read b1
        if (t + 1 < NT) STG(t + 1, 0, 1);
        __builtin_amdgcn_s_barrier();
        asm volatile("s_waitcnt lgkmcnt(0)" ::: "memory");
        __builtin_amdgcn_s_setprio(1); MM(0, 0, b0); __builtin_amdgcn_s_setprio(0);
        LDB(b1, 1, bb2);
        __builtin_amdgcn_s_barrier();
        // phase 1: MM(0,1)=A0*b1; read A1
        if (t + 2 < NT) STG(t + 2, 1, 0);
        __builtin_amdgcn_s_barrier();
        asm volatile("s_waitcnt lgkmcnt(0)" ::: "memory");
        __builtin_amdgcn_s_setprio(1); MM(0, 1, b1); __builtin_amdgcn_s_setprio(0);
        LDA(1, ab);
        __builtin_amdgcn_s_barrier();
        // phase 2: MM(1,1)=A1*b1
        if (t + 2 < NT) STG(t + 2, 1, 1);
        __builtin_amdgcn_s_barrier();
        asm volatile("s_waitcnt lgkmcnt(0)" ::: "memory");
        __builtin_amdgcn_s_setprio(1); MM(1, 1, b1); __builtin_amdgcn_s_setprio(0);
        __builtin_amdgcn_s_barrier();
        // phase 3: MM(1,0)=A1*b0; boundary vmcnt(6); post-MFMA next A0,b0
        if (t + 2 < NT) {
            STG(t + 2, 0, 0);
            asm volatile("s_waitcnt vmcnt(6)" ::: "memory");
        } else {
            asm volatile("s_waitcnt vmcnt(0)" ::: "memory");
        }
        __builtin_amdgcn_s_barrier();
        __builtin_amdgcn_s_setprio(1); MM(1, 0, b0); __builtin_amdgcn_s_setprio(0);
        if (t + 1 < NT) { LDA(0, nab); LDB(b0, 0, nab + 16384); }
        __builtin_amdgcn_s_barrier();
    }

    // epilogue
    if constexpr (MODE == 0) {
        const int grp = tn * 2 + (wn >> 7);
        const int which = grp >> 4, hd = grp & 15;
        const int n64 = wn & 64;
        if (which == 2) {
            const size_t bz = (size_t)((tm >> 4) * 256 + hd * 16 + (tm & 15));
            u16* tdst = (u16*)aux + bz * 32768;
            #pragma unroll
            for (int a = 0; a < 8; a++) {
                const int mm = wm + (a >> 2) * 64 + (a & 3) * 16 + quad * 4;
                #pragma unroll
                for (int b = 0; b < 4; b++) {
                    const int d = n64 + (b >> 1) * 32 + (b & 1) * 16 + cl;
                    u16 p[4];
                    #pragma unroll
                    for (int r = 0; r < 4; r++) {
                        const float x = acc[a][b][r];
                        p[r] = f2bf(x / (1.f + __expf(-x)));
                    }
                    uint2 pk;
                    pk.x = (unsigned)p[0] | ((unsigned)p[1] << 16);
                    pk.y = (unsigned)p[2] | ((unsigned)p[3] << 16);
                    *(uint2*)&tdst[(size_t)d * 256 + mm] = pk;
                }
            }
            return;
        }
        u16* dst = (which == 0) ? (u16*)Cv
                 : (which == 1) ? (u16*)Cv + (size_t)16777216   // k slot (S1)
                                : (u16*)aux2;                   // gate slot
        #pragma unroll
        for (int a = 0; a < 8; a++)
            #pragma unroll
            for (int b = 0; b < 4; b++)
                #pragma unroll
                for (int r = 0; r < 4; r++) {
                    const int m = tm * 256 + wm + (a >> 2) * 64 + (a & 3) * 16 + quad * 4 + r;
                    const int col = hd * 128 + n64 + (b >> 1) * 32 + (b & 1) * 16 + cl;
                    const float x = acc[a][b][r];
                    const float v = (which == 3) ? 1.f / (1.f + __expf(-x))
                                                 : x / (1.f + __expf(-x));
                    dst[(size_t)m * HID + col] = f2bf(v);
                }
        return;
    } else {
        float* C = (float*)Cv;
        #pragma unroll
        for (int a = 0; a < 8; a++)
            #pragma unroll
            for (int b = 0; b < 4; b++)
                #pragma unroll
                for (int r = 0; r < 4; r++) {
                    const int m = tm * 256 + wm + (a >> 2) * 64 + (a & 3) * 16 + quad * 4 + r;
                    const int n = tn * 256 + wn + (b >> 1) * 32 + (b & 1) * 16 + cl;
                    C[(size_t)m * HID + n] = acc[a][b][r];
                }
    }
}

// ---------------------------------------------------------------------------
// Generic 128x128-tile NT GEMM (kept for M_KVT).
// ---------------------------------------------------------------------------
#define M_KVT   4

template <int MODE>
__global__ __launch_bounds__(256) void gemm_nt(const u16* __restrict__ A,
                                               const u16* __restrict__ Bm,
                                               void* __restrict__ Cv,
                                               const float* __restrict__ slope,
                                               int bz0,
                                               void* __restrict__ aux,
                                               void* __restrict__ aux2) {
    const int tid = threadIdx.x;
    const int bz  = blockIdx.z + bz0;

    __shared__ u16 smem[8192];            // As/Bs staging, 16,384 B
    u16 (*As)[32] = (u16(*)[32])smem;
    u16 (*Bs)[32] = (u16(*)[32])(smem + 4096);

    const int lane = tid & 63, wv = tid >> 6;
    const int wm = (wv & 1) * 64, wn = (wv >> 1) * 64;
    const int quad = lane >> 4, cl = lane & 15;
    const int lr = lane >> 2;
    const int lc = (lane & 3) * 8;
    u16* lA = &As[wv * 32][0];
    u16* lB = &Bs[wv * 32][0];

    f32x4 acc[4][4];
    const f32x4 zero = {0.f, 0.f, 0.f, 0.f};
    #pragma unroll
    for (int mi = 0; mi < 4; mi++)
        #pragma unroll
        for (int ni = 0; ni < 4; ni++) acc[mi][ni] = zero;

    // M_KVT: A = vT[bz], B = kTs[bz], both ld 256, kmax 256
    const u16* Ab = A + (size_t)bz * 32768;
    const u16* Bb = Bm + (size_t)bz * 32768;
    const u16* gA = Ab + (size_t)(wv * 32 + lr) * 256 + lc;
    const u16* gB = Bb + (size_t)(wv * 32 + lr) * 256 + lc;

    for (int k0 = 0; k0 < 256; k0 += 32) {
        __syncthreads();
        gld16(gA + k0,                  lA);
        gld16(gA + k0 + (size_t)16 * 256, lA + 16 * 32);
        gld16(gB + k0,                  lB);
        gld16(gB + k0 + (size_t)16 * 256, lB + 16 * 32);
        __syncthreads();
        const int ko = quad * 8;
        bf16x8 af[4], bfv[4];
        #pragma unroll
        for (int mi = 0; mi < 4; mi++) af[mi] = *(const bf16x8*)&As[wm + mi * 16 + cl][ko];
        #pragma unroll
        for (int ni = 0; ni < 4; ni++) bfv[ni] = *(const bf16x8*)&Bs[wn + ni * 16 + cl][ko];
        #pragma unroll
        for (int mi = 0; mi < 4; mi++)
            #pragma unroll
            for (int ni = 0; ni < 4; ni++)
                acc[mi][ni] = __builtin_amdgcn_mfma_f32_16x16x32_bf16(af[mi], bfv[ni], acc[mi][ni], 0, 0, 0);
    }

    #pragma unroll
    for (int mi = 0; mi < 4; mi++)
        #pragma unroll
        for (int ni = 0; ni < 4; ni++)
            #pragma unroll
            for (int r = 0; r < 4; r++) {
                const int m = wm + mi * 16 + quad * 4 + r;
                const int n = wn + ni * 16 + cl;
                ((float*)Cv)[(size_t)bz * 16384 + m * 128 + n] = acc[mi][ni][r];
            }
}

// ---------------------------------------------------------------------------
// FUSED P+INTRA: grid (2,1,512) = (row-half tm, -, bz); 256 thr = 4 waves 2x2.
// Per block (128 rows x 128 d of attn):
//   1. stage q once: q_lds[4 ks][128][32] (gemm_nt tile layout, 2-way free)
//   2. inter: acc = q @ S^T (Bs-staged ST chunks), then *= q_decay(row)
//   3. per 32-kv chunk (kmax = tm?256:128):
//      stage k-chunk [32][128] (row-XOR swizzled src) + vT chunk (Bs);
//      P-chunk = q@k^T via 16 MFMA (wave owns 64 rows x 16 kv; C-layout
//      col = kv); mask+decay+bf16 -> P_lds[128][32]; barrier;
//      acc += P @ vT^T via 16 MFMA (A-frags from P_lds).
// Numerics identical to the old P->global->INTRA path (bf16 P).
// ---------------------------------------------------------------------------
__global__ __launch_bounds__(256) void fused_pv(const u16* __restrict__ qb,
                                                const u16* __restrict__ kb,
                                                const u16* __restrict__ ST,
                                                const u16* __restrict__ vT,
                                                u16* __restrict__ attn,
                                                const float* __restrict__ slope) {
    __shared__ u16 smem[28672];   // q 16384 | k 4096 | P 4096 | Bs 4096
    u16* q_lds = smem;            // [4][128][32]
    u16* k_lds = smem + 16384;    // [32][128] row-XOR swizzled
    u16* P_lds = smem + 20480;    // [128][32]
    u16* Bs    = smem + 24576;    // [128][32]

    const int tm = blockIdx.x;           // row half within the 256-block
    const int bz = blockIdx.z;
    const int bb = bz >> 8, hh = (bz >> 4) & 15, jb = bz & 15;
    const float s_ = slope[hh];

    const int tid  = threadIdx.x;
    const int lane = tid & 63, wv = tid >> 6;
    const int quad = lane >> 4, cl = lane & 15;
    const int wm = (wv & 1) * 64, wn = (wv >> 1) * 64;
    const int lr = lane >> 2, lc = (lane & 3) * 8;
    const int pcb = (wv >> 1) * 16;      // P kv-col base for this wave

    const size_t rowbase = (size_t)(bb * SEQ + jb * 256);

    // ---- stage q: 4 ks x 2 gld16 (gemm_nt A-tile pattern, linear) ----
    const u16* gq = qb + (rowbase + tm * 128 + wv * 32 + lr) * HID + hh * 128 + lc;
    u16* lq = q_lds + wv * 1024 + lr * 32 + lc;
    #pragma unroll
    for (int ks = 0; ks < 4; ks++) {
        gld16(gq + ks * 32,                 lq + ks * 4096);
        gld16(gq + ks * 32 + 16 * HID,      lq + ks * 4096 + 512);
    }

    f32x4 acc[4][4];
    const f32x4 zero = {0.f, 0.f, 0.f, 0.f};
    #pragma unroll
    for (int mi = 0; mi < 4; mi++)
        #pragma unroll
        for (int ni = 0; ni < 4; ni++) acc[mi][ni] = zero;

    // ---- inter: acc = q @ S^T ----
    const u16* gS = ST + (size_t)bz * 16384 + (size_t)(wv * 32 + lr) * 128 + lc;
    u16* lB = Bs + wv * 1024 + lr * 32 + lc;
    #pragma unroll
    for (int ks = 0; ks < 4; ks++) {
        __syncthreads();
        gld16(gS + ks * 32,            lB);
        gld16(gS + ks * 32 + 16 * 128, lB + 512);
        __syncthreads();
        bf16x8 af[4], bfv[4];
        #pragma unroll
        for (int mi = 0; mi < 4; mi++)
            af[mi] = *(const bf16x8*)&q_lds[ks * 4096 + (wm + mi * 16 + cl) * 32 + quad * 8];
        #pragma unroll
        for (int ni = 0; ni < 4; ni++)
            bfv[ni] = *(const bf16x8*)&Bs[(wn + ni * 16 + cl) * 32 + quad * 8];
        #pragma unroll
        for (int mi = 0; mi < 4; mi++)
            #pragma unroll
            for (int ni = 0; ni < 4; ni++)
                acc[mi][ni] = __builtin_amdgcn_mfma_f32_16x16x32_bf16(af[mi], bfv[ni], acc[mi][ni], 0, 0, 0);
    }
    // q_decay scale
    #pragma unroll
    for (int mi = 0; mi < 4; mi++)
        #pragma unroll
        for (int r = 0; r < 4; r++) {
            const int m = tm * 128 + wm + mi * 16 + quad * 4 + r;
            const float qd = __expf(-s_ * (float)(m + 1));
            #pragma unroll
            for (int ni = 0; ni < 4; ni++) acc[mi][ni][r] *= qd;
        }

    // ---- intra: per 32-kv chunk, compute P then acc += P@v ----
    const int kmax = (tm == 0) ? 128 : 256;
    const u16* gV = vT + (size_t)bz * 32768 + (size_t)(wv * 32 + lr) * 256 + lc;
    // k staging addresses (row-XOR pre-swizzled global source, linear dest)
    const int krow = tid >> 4;                       // 0..15 per issue
    const int kcol = (((tid & 15) ^ (krow & 7)) * 8);
    u16* lk = k_lds + wv * 512 + lane * 8;
    const int kvr = pcb + cl;                        // this lane's P kv-row for B-frag

    for (int kv0 = 0; kv0 < kmax; kv0 += 32) {
        __syncthreads();
        gld16(kb + (rowbase + kv0 +      krow) * HID + hh * 128 + kcol, lk);
        gld16(kb + (rowbase + kv0 + 16 + krow) * HID + hh * 128 + kcol, lk + 2048);
        gld16(gV + kv0,            lB);
        gld16(gV + kv0 + 16 * 256, lB + 512);
        __syncthreads();
        // P-GEMM: C[m(64 rows @wm)][kv(16 cols @pcb)] over d=128
        f32x4 acc2[4];
        #pragma unroll
        for (int mi = 0; mi < 4; mi++) acc2[mi] = zero;
        #pragma unroll
        for (int ds = 0; ds < 4; ds++) {
            bf16x8 bk = *(const bf16x8*)&k_lds[kvr * 128 + (((ds * 4 + quad) ^ (kvr & 7)) * 8)];
            #pragma unroll
            for (int mi = 0; mi < 4; mi++) {
                bf16x8 aq = *(const bf16x8*)&q_lds[ds * 4096 + (wm + mi * 16 + cl) * 32 + quad * 8];
                acc2[mi] = __builtin_amdgcn_mfma_f32_16x16x32_bf16(aq, bk, acc2[mi], 0, 0, 0);
            }
        }
        // mask + decay + bf16 -> P_lds[128][32]
        #pragma unroll
        for (int mi = 0; mi < 4; mi++)
            #pragma unroll
            for (int r = 0; r < 4; r++) {
                const int row = wm + mi * 16 + quad * 4 + r;
                const int mb  = tm * 128 + row;
                const int kv  = kv0 + pcb + cl;
                const int d   = mb - kv;
                const float x = acc2[mi][r];
                P_lds[row * 32 + pcb + cl] = f2bf(d >= 0 ? x * __expf(-s_ * (float)d) : 0.f);
            }
        __syncthreads();
        // PV: acc += P @ vT^T
        bf16x8 afp[4], bfv[4];
        #pragma unroll
        for (int mi = 0; mi < 4; mi++)
            afp[mi] = *(const bf16x8*)&P_lds[(wm + mi * 16 + cl) * 32 + quad * 8];
        #pragma unroll
        for (int ni = 0; ni < 4; ni++)
            bfv[ni] = *(const bf16x8*)&Bs[(wn + ni * 16 + cl) * 32 + quad * 8];
        #pragma unroll
        for (int mi = 0; mi < 4; mi++)
            #pragma unroll
            for (int ni = 0; ni < 4; ni++)
                acc[mi][ni] = __builtin_amdgcn_mfma_f32_16x16x32_bf16(afp[mi], bfv[ni], acc[mi][ni], 0, 0, 0);
    }

    // ---- epilogue: attn write (verbatim M_INTRA) ----
    #pragma unroll
    for (int mi = 0; mi < 4; mi++)
        #pragma unroll
        for (int ni = 0; ni < 4; ni++)
            #pragma unroll
            for (int r = 0; r < 4; r++) {
                const int m = tm * 128 + wm + mi * 16 + quad * 4 + r;
                const int n = wn + ni * 16 + cl;
                attn[(rowbase + m) * HID + hh * 128 + n] = f2bf(acc[mi][ni][r]);
            }
}

// ---------------------------------------------------------------------------
// Per (b,h,block): kTs[d][m] = k[m][d] * exp(-s*(255-m))  (vectorized stores)
// ---------------------------------------------------------------------------
__global__ __launch_bounds__(256) void transpose_k(const u16* __restrict__ kb,
                                                   u16* __restrict__ kTs,
                                                   const float* __restrict__ slope) {
    __shared__ u16 t[128][137];   // pad 137: transposed-read lanes land 2-way max
    const int bz = blockIdx.x;
    const int bb = bz >> 8, hh = (bz >> 4) & 15, jb = bz & 15;
    const int tid = threadIdx.x;
    const float s_ = slope[hh];
    const u16* src = kb + ((size_t)(bb * SEQ + jb * 256)) * HID + hh * 128;
    u16* dst = kTs + (size_t)bz * 32768;

    for (int half = 0; half < 2; half++) {
        #pragma unroll
        for (int i = 0; i < 8; i++) {
            const int flat = tid + 256 * i;
            const int row = flat >> 4, c8 = (flat & 15) * 8;
            *(uint4*)&t[row][c8] = *(const uint4*)&src[(size_t)(half * 128 + row) * HID + c8];
        }
        __syncthreads();
        #pragma unroll
        for (int i = 0; i < 8; i++) {
            const int flat = tid + 256 * i;
            const int d = flat >> 4, mc = (flat & 15) * 8;
            u16 p[8];
            #pragma unroll
            for (int j = 0; j < 8; j++) {
                const int m = half * 128 + mc + j;
                p[j] = f2bf(bf2f(t[mc + j][d]) * __expf(-s_ * (float)(255 - m)));
            }
            uint4 pk;
            pk.x = (unsigned)p[0] | ((unsigned)p[1] << 16);
            pk.y = (unsigned)p[2] | ((unsigned)p[3] << 16);
            pk.z = (unsigned)p[4] | ((unsigned)p[5] << 16);
            pk.w = (unsigned)p[6] | ((unsigned)p[7] << 16);
            *(uint4*)&dst[(size_t)d * 256 + half * 128 + mc] = pk;
        }
        __syncthreads();
    }
}

// ---------------------------------------------------------------------------
// S_0 = 0; write S_j^T (bf16); S_{j+1} = e^{-256 s} S_j + KV_j
// ---------------------------------------------------------------------------
__global__ __launch_bounds__(256) void scan_kv(const float* __restrict__ KVT,
                                               u16* __restrict__ ST,
                                               const float* __restrict__ slope) {
    const int bh = blockIdx.x >> 4, ch = blockIdx.x & 15;
    const int off = ch * 1024 + threadIdx.x * 4;
    const float bd = __expf(-256.f * slope[bh & 15]);
    float4 st = {0.f, 0.f, 0.f, 0.f};
    for (int j = 0; j < 16; j++) {
        const size_t base = ((size_t)(bh * 16 + j)) * 16384 + off;
        uint2 o;
        o.x = (unsigned)f2bf(st.x) | ((unsigned)f2bf(st.y) << 16);
        o.y = (unsigned)f2bf(st.z) | ((unsigned)f2bf(st.w) << 16);
        *(uint2*)&ST[base] = o;
        const float4 kv = *(const float4*)&KVT[base];
        st.x = bd * st.x + kv.x;
        st.y = bd * st.y + kv.y;
        st.z = bd * st.z + kv.z;
        st.w = bd * st.w + kv.w;
    }
}

// ---------------------------------------------------------------------------
// y = gate * (attn * rsqrt(mean(attn^2)+eps)) * norm_w   (one WG per row)
// ---------------------------------------------------------------------------
__global__ __launch_bounds__(256) void rmsnorm_gate(const u16* __restrict__ attn,
                                                    const u16* __restrict__ gate,
                                                    const float* __restrict__ nw,
                                                    u16* __restrict__ y) {
    const int r = blockIdx.x, tid = threadIdx.x;
    const size_t base = (size_t)r * HID + tid * 8;
    const uint4 a = *(const uint4*)&attn[base];
    float x[8];
    x[0] = bf2f(a.x & 0xffff); x[1] = bf2f(a.x >> 16);
    x[2] = bf2f(a.y & 0xffff); x[3] = bf2f(a.y >> 16);
    x[4] = bf2f(a.z & 0xffff); x[5] = bf2f(a.z >> 16);
    x[6] = bf2f(a.w & 0xffff); x[7] = bf2f(a.w >> 16);
    float s = 0.f;
    #pragma unroll
    for (int i = 0; i < 8; i++) s += x[i] * x[i];
    #pragma unroll
    for (int off = 32; off > 0; off >>= 1) s += __shfl_down(s, off);
    __shared__ float red[4];
    if ((tid & 63) == 0) red[tid >> 6] = s;
    __syncthreads();
    const float tot = red[0] + red[1] + red[2] + red[3];
    const float sc = rsqrtf(tot * (1.f / 2048.f) + 1e-6f);
    const uint4 g = *(const uint4*)&gate[base];
    float gv[8];
    gv[0] = bf2f(g.x & 0xffff); gv[1] = bf2f(g.x >> 16);
    gv[2] = bf2f(g.y & 0xffff); gv[3] = bf2f(g.y >> 16);
    gv[4] = bf2f(g.z & 0xffff); gv[5] = bf2f(g.z >> 16);
    gv[6] = bf2f(g.w & 0xffff); gv[7] = bf2f(g.w >> 16);
    const float4 w0 = *(const float4*)&nw[tid * 8];
    const float4 w1 = *(const float4*)&nw[tid * 8 + 4];
    const float wv[8] = {w0.x, w0.y, w0.z, w0.w, w1.x, w1.y, w1.z, w1.w};
    u16 o[8];
    #pragma unroll
    for (int i = 0; i < 8; i++) o[i] = f2bf(gv[i] * x[i] * sc * wv[i]);
    uint4 ov;
    ov.x = (unsigned)o[0] | ((unsigned)o[1] << 16);
    ov.y = (unsigned)o[2] | ((unsigned)o[3] << 16);
    ov.z = (unsigned)o[4] | ((unsigned)o[5] << 16);
    ov.w = (unsigned)o[6] | ((unsigned)o[7] << 16);
    *(uint4*)&y[base] = ov;
}

// ---------------------------------------------------------------------------
extern "C" void kernel_launch(void* const* d_in, const int* in_sizes, int n_in,
                              void* d_out, int out_size, void* d_ws, size_t ws_size,
                              hipStream_t stream) {
    const float* hidden = (const float*)d_in[0];
    const float* slope  = (const float*)d_in[1];
    const float* w_qkv  = (const float*)d_in[2];
    const float* w_gate = (const float*)d_in[3];
    const float* w_out  = (const float*)d_in[4];
    const float* norm_w = (const float*)d_in[5];
    float* out = (float*)d_out;

    // 7 slots x 33,554,432 B = 234,881,024 B total
    char* w = (char*)d_ws;
    u16* qb   = (u16*)(w);                 // S0: q                 [QKV .. fused_pv]
    u16* kb   = (u16*)(w +  33554432);     // S1: k                 [QKV .. fused_pv]
    u16* kTs  = (u16*)(w +  67108864);     // S2: kTs               [transpose .. KVT]
    u16* hid_bf = (u16*)(w + 100663296);   // S3: hidden bf16       [cast .. QKV]
    u16* vT   = (u16*)(w + 134217728);     // S4: vT (via QKV)      [QKV .. fused_pv]
    u16* gate = (u16*)(w + 167772160);     // S5: gate (via QKV)    [QKV .. rms]
    u16* wqkv_bf  = (u16*)(w + 201326592); // S6: w_qkv bf16 25.17M [cast .. QKV]
    u16* wgate_bf = (u16*)(w + 201326592 + 25165824); // S6 tail 8.39M, contiguous
    // aliases (disjoint lifetimes):
    float* KVT  = (float*)hid_bf;          // S3: KV^T fp32         [KVT .. scan]
    u16*   ST   = kTs;                     // S2: S^T bf16 16.8M    [scan .. fused_pv]
    u16*   wout_bf = kb;                   // S1: w_out bf16        [cast .. OUT]
    u16*   attn = wqkv_bf;                 // S6: attn              [fused_pv .. rms]
    u16*   y    = kTs;                     // S2: y                 [rms .. OUT]

    static bool s_attr = false;
    if (!s_attr) {
        (void)hipFuncSetAttribute((const void*)gemm256<0>,
                                  hipFuncAttributeMaxDynamicSharedMemorySize, 131072);
        (void)hipFuncSetAttribute((const void*)gemm256<1>,
                                  hipFuncAttributeMaxDynamicSharedMemorySize, 131072);
        s_attr = true;
    }

    castk<<<16384, 256, 0, stream>>>(hidden, hid_bf);
    castk<<<12288, 256, 0, stream>>>(w_qkv,  wqkv_bf);
    castk<<< 4096, 256, 0, stream>>>(w_gate, wgate_bf);

    // fused qkv+gate: B = [w_qkv ; w_gate] (8192 x 2048 contiguous)
    gemm256<0><<<dim3(1024), dim3(512), 131072, stream>>>(hid_bf, wqkv_bf, qb, vT, gate);
    transpose_k     <<<512,             256, 0, stream>>>(kb, kTs, slope);
    gemm_nt<M_KVT ><<<dim3(1, 1, 512),  256, 0, stream>>>(vT, kTs, KVT, slope, 0, nullptr, nullptr);
    scan_kv         <<<512,             256, 0, stream>>>(KVT, ST, slope);
    fused_pv        <<<dim3(2, 1, 512), 256, 0, stream>>>(qb, kb, ST, vT, attn, slope);
    castk<<< 4096, 256, 0, stream>>>(w_out, wout_bf);
    rmsnorm_gate    <<<8192,            256, 0, stream>>>(attn, gate, norm_w, y);
    gemm256<1><<<dim3(256), dim3(512), 131072, stream>>>(y, wout_bf, (void*)out, nullptr, nullptr);
}